// Round 1
// baseline (1013.489 us; speedup 1.0000x reference)
//
#include <hip/hip_runtime.h>
#include <hip/hip_bf16.h>

#define N_NODES 50000
#define N_EDGES 800000
#define NFEAT 512
#define NHID 128
#define NCLASS 40
#define BN_EPS 1e-5f

// ---------------------------------------------------------------------------
// Edge-index dtype detection: reference dtype is int64 (values < 50000, so
// high 32-bit words are all zero). If the harness hands us int32 instead,
// odd uint32 positions hold real edge values (~never zero). Decide at runtime.
__global__ void k_detect(const unsigned int* __restrict__ words, int* __restrict__ flag) {
    __shared__ int s_any;
    if (threadIdx.x == 0) s_any = 0;
    __syncthreads();
    unsigned int v = words[2 * threadIdx.x + 1];  // positions 1,3,...,511
    if (v != 0) atomicAdd(&s_any, 1);
    __syncthreads();
    if (threadIdx.x == 0) *flag = (s_any == 0) ? 1 : 0;  // 1 => int64 layout
}

__global__ void k_convert(const unsigned int* __restrict__ words, const int* __restrict__ flag,
                          int* __restrict__ row, int* __restrict__ col) {
    int i = blockIdx.x * blockDim.x + threadIdx.x;
    if (i >= 2 * N_EDGES) return;
    int f = *flag;
    unsigned int v = f ? words[2 * (size_t)i] : words[i];
    if (i < N_EDGES) row[i] = (int)v;
    else             col[i - N_EDGES] = (int)v;
}

// ---------------------------------------------------------------------------
// gcn_norm: deg[c] = 1 (self loop) + sum of ew into c; dinv = rsqrt(deg)
__global__ void k_init_node(float* __restrict__ deg, int* __restrict__ counts) {
    int i = blockIdx.x * blockDim.x + threadIdx.x;
    if (i < N_NODES) { deg[i] = 1.0f; counts[i] = 0; }
}

__global__ void k_accum(const int* __restrict__ col, const float* __restrict__ ew,
                        float* __restrict__ deg, int* __restrict__ counts) {
    int e = blockIdx.x * blockDim.x + threadIdx.x;
    if (e < N_EDGES) {
        int c = col[e];
        atomicAdd(&deg[c], ew[e]);
        atomicAdd(&counts[c], 1);
    }
}

__global__ void k_dinv(const float* __restrict__ deg, float* __restrict__ dinv) {
    int i = blockIdx.x * blockDim.x + threadIdx.x;
    if (i < N_NODES) dinv[i] = rsqrtf(fmaxf(deg[i], 1e-30f));  // deg >= 1 always
}

// Single-block exclusive scan of counts -> colptr (and cursor copy).
// Thread t owns a contiguous chunk; 1 block-level Hillis-Steele over 256 sums.
__global__ void k_scan(const int* __restrict__ counts, int* __restrict__ colptr,
                       int* __restrict__ cursor) {
    const int C = (N_NODES + 255) / 256;  // 196
    int t = threadIdx.x;
    int beg = t * C, end = min(beg + C, N_NODES);
    int s = 0;
    for (int i = beg; i < end; i++) s += counts[i];
    __shared__ int buf[256];
    buf[t] = s;
    __syncthreads();
    for (int ofs = 1; ofs < 256; ofs <<= 1) {
        int u = (t >= ofs) ? buf[t - ofs] : 0;
        __syncthreads();
        if (t >= ofs) buf[t] += u;
        __syncthreads();
    }
    int run = buf[t] - s;  // exclusive prefix of this chunk
    for (int i = beg; i < end; i++) {
        int v = counts[i];
        colptr[i] = run;
        cursor[i] = run;
        run += v;
    }
    if (t == 255) colptr[N_NODES] = run;
}

__global__ void k_scatter(const int* __restrict__ row, const int* __restrict__ col,
                          const float* __restrict__ ew, const float* __restrict__ dinv,
                          int* __restrict__ cursor, int* __restrict__ erow,
                          float* __restrict__ enorm) {
    int e = blockIdx.x * blockDim.x + threadIdx.x;
    if (e < N_EDGES) {
        int c = col[e], r = row[e];
        int p = atomicAdd(&cursor[c], 1);
        erow[p] = r;
        enorm[p] = dinv[r] * ew[e] * dinv[c];
    }
}

// ---------------------------------------------------------------------------
// fp32 tiled GEMM: Out[M,128] = A[M,K] @ W[K,128]. BM=64 BN=128 BK=16, 8x4/thread.
template <int K>
__global__ __launch_bounds__(256) void k_gemm(const float* __restrict__ A,
                                              const float* __restrict__ W,
                                              float* __restrict__ Out, int M) {
    __shared__ float As[16][64 + 1];
    __shared__ float Bs[16][128];
    int tid = threadIdx.x;
    int m0 = blockIdx.x * 64;
    int r0 = (tid >> 5) << 3;   // (tid/32)*8
    int c0 = (tid & 31) << 2;   // (tid%32)*4
    int arow = tid >> 2;        // 0..63
    int acol4 = (tid & 3) << 2; // 0,4,8,12
    int brow = tid >> 4;        // 0..15
    int bcol = (tid & 15) << 3; // 0..120 step 8
    float acc[8][4] = {};
    for (int kt = 0; kt < K; kt += 16) {
        float4 av = make_float4(0.f, 0.f, 0.f, 0.f);
        if (m0 + arow < M)
            av = *(const float4*)&A[(size_t)(m0 + arow) * K + kt + acol4];
        As[acol4 + 0][arow] = av.x;
        As[acol4 + 1][arow] = av.y;
        As[acol4 + 2][arow] = av.z;
        As[acol4 + 3][arow] = av.w;
        float4 b0 = *(const float4*)&W[(size_t)(kt + brow) * 128 + bcol];
        float4 b1 = *(const float4*)&W[(size_t)(kt + brow) * 128 + bcol + 4];
        *(float4*)&Bs[brow][bcol] = b0;
        *(float4*)&Bs[brow][bcol + 4] = b1;
        __syncthreads();
#pragma unroll
        for (int kk = 0; kk < 16; kk++) {
            float a[8], b[4];
#pragma unroll
            for (int i = 0; i < 8; i++) a[i] = As[kk][r0 + i];
#pragma unroll
            for (int j = 0; j < 4; j++) b[j] = Bs[kk][c0 + j];
#pragma unroll
            for (int i = 0; i < 8; i++)
#pragma unroll
                for (int j = 0; j < 4; j++) acc[i][j] += a[i] * b[j];
        }
        __syncthreads();
    }
#pragma unroll
    for (int i = 0; i < 8; i++) {
        int m = m0 + r0 + i;
        if (m < M) {
            float4 o = make_float4(acc[i][0], acc[i][1], acc[i][2], acc[i][3]);
            *(float4*)&Out[(size_t)m * 128 + c0] = o;
        }
    }
}

// ---------------------------------------------------------------------------
// CSR aggregation, one wave per node: out[i] = bias + dinv[i]^2*h[i] + sum norm_e*h[row_e]
__global__ __launch_bounds__(256) void k_aggregate(
    const float* __restrict__ h, const int* __restrict__ colptr,
    const int* __restrict__ erow, const float* __restrict__ enorm,
    const float* __restrict__ dinv, const float* __restrict__ bias,
    float* __restrict__ out, int relu) {
    int wave = (blockIdx.x * blockDim.x + threadIdx.x) >> 6;
    int lane = threadIdx.x & 63;
    if (wave >= N_NODES) return;
    int i = wave;
    float di = dinv[i];
    float selfw = di * di;
    float a0 = selfw * h[(size_t)i * 128 + lane];
    float a1 = selfw * h[(size_t)i * 128 + 64 + lane];
    int beg = colptr[i], end = colptr[i + 1];
    for (int e = beg; e < end; e++) {
        int r = erow[e];
        float w = enorm[e];
        a0 += w * h[(size_t)r * 128 + lane];
        a1 += w * h[(size_t)r * 128 + 64 + lane];
    }
    a0 += bias[lane];
    a1 += bias[64 + lane];
    if (relu) { a0 = fmaxf(a0, 0.f); a1 = fmaxf(a1, 0.f); }
    out[(size_t)i * 128 + lane] = a0;
    out[(size_t)i * 128 + 64 + lane] = a1;
}

// ---------------------------------------------------------------------------
// BatchNorm (training-mode, biased var) over node dim
__global__ void k_zero_stats(float* __restrict__ sums, float* __restrict__ sumsq) {
    if (threadIdx.x < 128) { sums[threadIdx.x] = 0.f; sumsq[threadIdx.x] = 0.f; }
}

__global__ __launch_bounds__(256) void k_bnstats(const float* __restrict__ x,
                                                 float* __restrict__ sums,
                                                 float* __restrict__ sumsq) {
    int c = threadIdx.x & 127;
    int half = threadIdx.x >> 7;  // 0 or 1
    int r0 = blockIdx.x * 256;
    int rend = min(r0 + 256, N_NODES);
    float s = 0.f, s2 = 0.f;
    for (int r = r0 + half; r < rend; r += 2) {
        float v = x[(size_t)r * 128 + c];
        s += v;
        s2 += v * v;
    }
    __shared__ float sh[256], sh2[256];
    sh[threadIdx.x] = s;
    sh2[threadIdx.x] = s2;
    __syncthreads();
    if (half == 0) {
        atomicAdd(&sums[c], sh[threadIdx.x] + sh[threadIdx.x + 128]);
        atomicAdd(&sumsq[c], sh2[threadIdx.x] + sh2[threadIdx.x + 128]);
    }
}

__global__ void k_bnfinal(const float* __restrict__ sums, const float* __restrict__ sumsq,
                          const float* __restrict__ g, const float* __restrict__ be,
                          float* __restrict__ scale, float* __restrict__ shift) {
    int c = threadIdx.x;
    if (c < 128) {
        const float invn = 1.0f / (float)N_NODES;
        float mu = sums[c] * invn;
        float var = sumsq[c] * invn - mu * mu;
        float iv = rsqrtf(var + BN_EPS);
        float sc = g[c] * iv;
        scale[c] = sc;
        shift[c] = be[c] - mu * sc;
    }
}

__global__ __launch_bounds__(256) void k_bnapply(const float* __restrict__ x,
                                                 const float* __restrict__ scale,
                                                 const float* __restrict__ shift,
                                                 float* __restrict__ y) {
    int i = blockIdx.x * blockDim.x + threadIdx.x;  // float4 index
    const int total = N_NODES * 128 / 4;
    if (i < total) {
        float4 v = ((const float4*)x)[i];
        int c = (i << 2) & 127;
        v.x = v.x * scale[c + 0] + shift[c + 0];
        v.y = v.y * scale[c + 1] + shift[c + 1];
        v.z = v.z * scale[c + 2] + shift[c + 2];
        v.w = v.w * scale[c + 3] + shift[c + 3];
        ((float4*)y)[i] = v;
    }
}

// ---------------------------------------------------------------------------
// Head: logits = x3 @ linW + linb; softmax fused. 64 nodes/block, 4 lanes/node.
__global__ __launch_bounds__(256) void k_logits(const float* __restrict__ x3,
                                                const float* __restrict__ linW,
                                                const float* __restrict__ linb,
                                                float* __restrict__ logits,
                                                float* __restrict__ probs) {
    __shared__ float Xs[64][129];
    __shared__ float Ws[128 * 40];
    int tid = threadIdx.x;
    int m0 = blockIdx.x * 64;
    for (int q = tid; q < 1280; q += 256)
        *(float4*)&Ws[q * 4] = *(const float4*)&linW[q * 4];
    for (int q = tid; q < 2048; q += 256) {
        int r = q >> 5, cf = (q & 31) << 2;
        float4 v = make_float4(0.f, 0.f, 0.f, 0.f);
        if (m0 + r < N_NODES) v = *(const float4*)&x3[(size_t)(m0 + r) * 128 + cf];
        *(float4*)&Xs[r][cf] = v;
    }
    __syncthreads();
    int r = tid >> 2;
    int cg = tid & 3;
    int cbase = cg * 10;
    float acc[10] = {};
    for (int k = 0; k < 128; k++) {
        float a = Xs[r][k];
#pragma unroll
        for (int j = 0; j < 10; j++) acc[j] += a * Ws[k * 40 + cbase + j];
    }
#pragma unroll
    for (int j = 0; j < 10; j++) acc[j] += linb[cbase + j];
    // softmax over 40 classes = 4 lanes x 10
    float m = acc[0];
#pragma unroll
    for (int j = 1; j < 10; j++) m = fmaxf(m, acc[j]);
    m = fmaxf(m, __shfl_xor(m, 1));
    m = fmaxf(m, __shfl_xor(m, 2));
    float ex[10];
    float s = 0.f;
#pragma unroll
    for (int j = 0; j < 10; j++) { ex[j] = expf(acc[j] - m); s += ex[j]; }
    s += __shfl_xor(s, 1);
    s += __shfl_xor(s, 2);
    float inv = 1.0f / s;
    int mrow = m0 + r;
    if (mrow < N_NODES) {
#pragma unroll
        for (int j = 0; j < 10; j++) {
            logits[(size_t)mrow * 40 + cbase + j] = acc[j];
            probs[(size_t)mrow * 40 + cbase + j] = ex[j] * inv;
        }
    }
}

// ---------------------------------------------------------------------------
extern "C" void kernel_launch(void* const* d_in, const int* in_sizes, int n_in,
                              void* d_out, int out_size, void* d_ws, size_t ws_size,
                              hipStream_t stream) {
    const float* x = (const float*)d_in[0];
    const unsigned int* eidx = (const unsigned int*)d_in[1];
    const float* ew = (const float*)d_in[2];
    const float* W1 = (const float*)d_in[3];
    const float* b1 = (const float*)d_in[4];
    const float* W2 = (const float*)d_in[5];
    const float* b2 = (const float*)d_in[6];
    const float* W3 = (const float*)d_in[7];
    const float* b3 = (const float*)d_in[8];
    const float* g1 = (const float*)d_in[9];
    const float* be1 = (const float*)d_in[10];
    const float* g2 = (const float*)d_in[11];
    const float* be2 = (const float*)d_in[12];
    const float* g3 = (const float*)d_in[13];
    const float* be3 = (const float*)d_in[14];
    const float* linW = (const float*)d_in[15];
    const float* linb = (const float*)d_in[16];

    float* out = (float*)d_out;
    float* logits = out;
    float* probs = out + (size_t)N_NODES * NCLASS;
    float* x3out = out + 2 * (size_t)N_NODES * NCLASS;

    char* ws = (char*)d_ws;
    size_t off = 0;
    auto take = [&](size_t bytes) -> char* {
        char* p = ws + off;
        off += (bytes + 255) & ~(size_t)255;
        return p;
    };
    int* row32 = (int*)take((size_t)N_EDGES * 4);
    int* col32 = (int*)take((size_t)N_EDGES * 4);
    int* colptr = (int*)take((size_t)(N_NODES + 1) * 4);
    int* cursor = (int*)take((size_t)N_NODES * 4);
    int* counts = (int*)take((size_t)N_NODES * 4);
    int* erow = (int*)take((size_t)N_EDGES * 4);
    float* enorm = (float*)take((size_t)N_EDGES * 4);
    float* deg = (float*)take((size_t)N_NODES * 4);
    float* dinv = (float*)take((size_t)N_NODES * 4);
    float* hbuf = (float*)take((size_t)N_NODES * NHID * 4);
    float* abuf = (float*)take((size_t)N_NODES * NHID * 4);
    float* xbuf = (float*)take((size_t)N_NODES * NHID * 4);
    float* sums = (float*)take(128 * 4);
    float* sumsq = (float*)take(128 * 4);
    float* scale = (float*)take(128 * 4);
    float* shift = (float*)take(128 * 4);
    int* flag = (int*)take(4);
    (void)ws_size; (void)n_in; (void)in_sizes; (void)out_size;

    const int TPB = 256;
    int grid_e = (N_EDGES + TPB - 1) / TPB;
    int grid_n = (N_NODES + TPB - 1) / TPB;
    int grid_gemm = (N_NODES + 63) / 64;          // 782
    int grid_agg = (N_NODES * 64) / TPB;          // 12500
    int grid_bn = (N_NODES + 255) / 256;          // 196
    int grid_apply = (N_NODES * NHID / 4 + TPB - 1) / TPB;

    // graph preprocessing
    k_detect<<<1, 256, 0, stream>>>(eidx, flag);
    k_convert<<<(2 * N_EDGES + TPB - 1) / TPB, TPB, 0, stream>>>(eidx, flag, row32, col32);
    k_init_node<<<grid_n, TPB, 0, stream>>>(deg, counts);
    k_accum<<<grid_e, TPB, 0, stream>>>(col32, ew, deg, counts);
    k_dinv<<<grid_n, TPB, 0, stream>>>(deg, dinv);
    k_scan<<<1, 256, 0, stream>>>(counts, colptr, cursor);
    k_scatter<<<grid_e, TPB, 0, stream>>>(row32, col32, ew, dinv, cursor, erow, enorm);

    // layer 1
    k_gemm<NFEAT><<<grid_gemm, TPB, 0, stream>>>(x, W1, hbuf, N_NODES);
    k_aggregate<<<grid_agg, TPB, 0, stream>>>(hbuf, colptr, erow, enorm, dinv, b1, abuf, 1);
    k_zero_stats<<<1, 128, 0, stream>>>(sums, sumsq);
    k_bnstats<<<grid_bn, TPB, 0, stream>>>(abuf, sums, sumsq);
    k_bnfinal<<<1, 128, 0, stream>>>(sums, sumsq, g1, be1, scale, shift);
    k_bnapply<<<grid_apply, TPB, 0, stream>>>(abuf, scale, shift, xbuf);

    // layer 2
    k_gemm<NHID><<<grid_gemm, TPB, 0, stream>>>(xbuf, W2, hbuf, N_NODES);
    k_aggregate<<<grid_agg, TPB, 0, stream>>>(hbuf, colptr, erow, enorm, dinv, b2, abuf, 1);
    k_zero_stats<<<1, 128, 0, stream>>>(sums, sumsq);
    k_bnstats<<<grid_bn, TPB, 0, stream>>>(abuf, sums, sumsq);
    k_bnfinal<<<1, 128, 0, stream>>>(sums, sumsq, g2, be2, scale, shift);
    k_bnapply<<<grid_apply, TPB, 0, stream>>>(abuf, scale, shift, xbuf);

    // layer 3 (no relu), x3 written straight into d_out
    k_gemm<NHID><<<grid_gemm, TPB, 0, stream>>>(xbuf, W3, hbuf, N_NODES);
    k_aggregate<<<grid_agg, TPB, 0, stream>>>(hbuf, colptr, erow, enorm, dinv, b3, abuf, 0);
    k_zero_stats<<<1, 128, 0, stream>>>(sums, sumsq);
    k_bnstats<<<grid_bn, TPB, 0, stream>>>(abuf, sums, sumsq);
    k_bnfinal<<<1, 128, 0, stream>>>(sums, sumsq, g3, be3, scale, shift);
    k_bnapply<<<grid_apply, TPB, 0, stream>>>(abuf, scale, shift, x3out);

    // head: logits + softmax
    k_logits<<<grid_gemm, TPB, 0, stream>>>(x3out, linW, linb, logits, probs);
}

// Round 2
// 889.376 us; speedup vs baseline: 1.1396x; 1.1396x over previous
//
#include <hip/hip_runtime.h>
#include <hip/hip_bf16.h>

#define N_NODES 50000
#define N_EDGES 800000
#define NFEAT 512
#define NHID 128
#define NCLASS 40
#define BN_EPS 1e-5f

typedef __attribute__((ext_vector_type(8))) short short8;
typedef __attribute__((ext_vector_type(4))) float f32x4;

__device__ __forceinline__ unsigned short f2b(float f) {
    unsigned int u = __float_as_uint(f);
    u += 0x7fff + ((u >> 16) & 1);   // RTNE
    return (unsigned short)(u >> 16);
}

// ---------------------------------------------------------------------------
// Edge-index dtype detection (int64 ref layout vs int32 handed by harness).
__global__ void k_detect(const unsigned int* __restrict__ words, int* __restrict__ flag) {
    __shared__ int s_any;
    if (threadIdx.x == 0) s_any = 0;
    __syncthreads();
    unsigned int v = words[2 * threadIdx.x + 1];
    if (v != 0) atomicAdd(&s_any, 1);
    __syncthreads();
    if (threadIdx.x == 0) *flag = (s_any == 0) ? 1 : 0;  // 1 => int64 layout
}

__global__ void k_convert(const unsigned int* __restrict__ words, const int* __restrict__ flag,
                          int* __restrict__ row, int* __restrict__ col) {
    int i = blockIdx.x * blockDim.x + threadIdx.x;
    if (i >= 2 * N_EDGES) return;
    int f = *flag;
    unsigned int v = f ? words[2 * (size_t)i] : words[i];
    if (i < N_EDGES) row[i] = (int)v;
    else             col[i - N_EDGES] = (int)v;
}

// ---------------------------------------------------------------------------
__global__ void k_init_node(float* __restrict__ deg, int* __restrict__ counts) {
    int i = blockIdx.x * blockDim.x + threadIdx.x;
    if (i < N_NODES) { deg[i] = 1.0f; counts[i] = 0; }
}

__global__ void k_accum(const int* __restrict__ col, const float* __restrict__ ew,
                        float* __restrict__ deg, int* __restrict__ counts) {
    int e = blockIdx.x * blockDim.x + threadIdx.x;
    if (e < N_EDGES) {
        int c = col[e];
        atomicAdd(&deg[c], ew[e]);
        atomicAdd(&counts[c], 1);
    }
}

__global__ void k_dinv(const float* __restrict__ deg, float* __restrict__ dinv) {
    int i = blockIdx.x * blockDim.x + threadIdx.x;
    if (i < N_NODES) dinv[i] = rsqrtf(fmaxf(deg[i], 1e-30f));
}

__global__ void k_scan(const int* __restrict__ counts, int* __restrict__ colptr,
                       int* __restrict__ cursor) {
    const int C = (N_NODES + 255) / 256;
    int t = threadIdx.x;
    int beg = t * C, end = min(beg + C, N_NODES);
    int s = 0;
    for (int i = beg; i < end; i++) s += counts[i];
    __shared__ int buf[256];
    buf[t] = s;
    __syncthreads();
    for (int ofs = 1; ofs < 256; ofs <<= 1) {
        int u = (t >= ofs) ? buf[t - ofs] : 0;
        __syncthreads();
        if (t >= ofs) buf[t] += u;
        __syncthreads();
    }
    int run = buf[t] - s;
    for (int i = beg; i < end; i++) {
        int v = counts[i];
        colptr[i] = run;
        cursor[i] = run;
        run += v;
    }
    if (t == 255) colptr[N_NODES] = run;
}

__global__ void k_scatter(const int* __restrict__ row, const int* __restrict__ col,
                          const float* __restrict__ ew, const float* __restrict__ dinv,
                          int* __restrict__ cursor, int* __restrict__ erow,
                          float* __restrict__ enorm) {
    int e = blockIdx.x * blockDim.x + threadIdx.x;
    if (e < N_EDGES) {
        int c = col[e], r = row[e];
        int p = atomicAdd(&cursor[c], 1);
        erow[p] = r;
        enorm[p] = dinv[r] * ew[e] * dinv[c];
    }
}

// ---------------------------------------------------------------------------
// Weight prep: fp32 W[K][128] -> bf16 W^T[128][K], for W1,W2,W3.
__global__ void k_prep_w(const float* __restrict__ W1, const float* __restrict__ W2,
                         const float* __restrict__ W3, unsigned short* __restrict__ W1t,
                         unsigned short* __restrict__ W2t, unsigned short* __restrict__ W3t) {
    int i = blockIdx.x * blockDim.x + threadIdx.x;
    if (i < 65536) {
        int k = i >> 7, n = i & 127;
        W1t[n * 512 + k] = f2b(W1[i]);
    } else if (i < 81920) {
        int j = i - 65536; int k = j >> 7, n = j & 127;
        W2t[n * 128 + k] = f2b(W2[j]);
    } else if (i < 98304) {
        int j = i - 81920; int k = j >> 7, n = j & 127;
        W3t[n * 128 + k] = f2b(W3[j]);
    }
}

// ---------------------------------------------------------------------------
// bf16 MFMA GEMM: Out[M,128] = A[M,K] @ W[K,128]. BM=128, BN=128, BK=32.
// A fp32 in global (optionally BN scale/shift fused), converted to bf16 while
// staging. Wt is bf16 W^T [128][K] so B^T staging is coalesced vector loads.
// LDS rows padded to 40 shorts (80 B) -> only 2-way bank aliasing (free).
template <int K, bool FUSE>
__global__ __launch_bounds__(256) void k_gemm_bf16(
    const float* __restrict__ A, const unsigned short* __restrict__ Wt,
    const float* __restrict__ scale, const float* __restrict__ shift,
    float* __restrict__ Out, int M) {
    __shared__ unsigned short As[128][40];
    __shared__ unsigned short Bs[128][40];
    __shared__ float s_sc[128], s_sh[128];
    int tid = threadIdx.x;
    int m0 = blockIdx.x * 128;
    if (FUSE) {
        if (tid < 128) { s_sc[tid] = scale[tid]; s_sh[tid] = shift[tid]; }
        __syncthreads();
    }
    int srow = tid >> 1;        // 0..127
    int skh = (tid & 1) << 4;   // 0 or 16
    int wave = tid >> 6, lane = tid & 63;
    int wm = (wave >> 1) * 64, wn = (wave & 1) * 64;
    int l15 = lane & 15, quad = lane >> 4;
    f32x4 acc[4][4] = {};
    bool arow_ok = (m0 + srow) < M;
    const float* arow_p = A + (size_t)(m0 + srow) * K + skh;
    const unsigned short* wrow_p = Wt + (size_t)srow * K + skh;
    for (int kt = 0; kt < K; kt += 32) {
        float v[16];
#pragma unroll
        for (int q = 0; q < 4; q++) {
            float4 t4 = make_float4(0.f, 0.f, 0.f, 0.f);
            if (arow_ok) t4 = *(const float4*)(arow_p + kt + q * 4);
            v[q * 4 + 0] = t4.x; v[q * 4 + 1] = t4.y;
            v[q * 4 + 2] = t4.z; v[q * 4 + 3] = t4.w;
        }
        if (FUSE) {
#pragma unroll
            for (int q = 0; q < 16; q++)
                v[q] = v[q] * s_sc[kt + skh + q] + s_sh[kt + skh + q];
        }
        unsigned int p[8];
#pragma unroll
        for (int q = 0; q < 8; q++)
            p[q] = (unsigned int)f2b(v[2 * q]) | ((unsigned int)f2b(v[2 * q + 1]) << 16);
        uint4 w0 = make_uint4(p[0], p[1], p[2], p[3]);
        uint4 w1 = make_uint4(p[4], p[5], p[6], p[7]);
        uint4 b0 = *(const uint4*)(wrow_p + kt);
        uint4 b1 = *(const uint4*)(wrow_p + kt + 8);
        *(uint4*)&As[srow][skh] = w0;
        *(uint4*)&As[srow][skh + 8] = w1;
        *(uint4*)&Bs[srow][skh] = b0;
        *(uint4*)&Bs[srow][skh + 8] = b1;
        __syncthreads();
        short8 a[4], b[4];
#pragma unroll
        for (int i = 0; i < 4; i++) a[i] = *(const short8*)&As[wm + i * 16 + l15][quad * 8];
#pragma unroll
        for (int j = 0; j < 4; j++) b[j] = *(const short8*)&Bs[wn + j * 16 + l15][quad * 8];
#pragma unroll
        for (int i = 0; i < 4; i++)
#pragma unroll
            for (int j = 0; j < 4; j++)
                acc[i][j] = __builtin_amdgcn_mfma_f32_16x16x32_bf16(a[i], b[j], acc[i][j], 0, 0, 0);
        __syncthreads();
    }
#pragma unroll
    for (int i = 0; i < 4; i++) {
        int mb = m0 + wm + i * 16 + quad * 4;
#pragma unroll
        for (int r = 0; r < 4; r++) {
            int m = mb + r;
            if (m < M) {
#pragma unroll
                for (int j = 0; j < 4; j++)
                    Out[(size_t)m * 128 + wn + j * 16 + l15] = acc[i][j][r];
            }
        }
    }
}

// ---------------------------------------------------------------------------
// CSR aggregation (fp32 exact): one wave per node.
__global__ __launch_bounds__(256) void k_aggregate(
    const float* __restrict__ h, const int* __restrict__ colptr,
    const int* __restrict__ erow, const float* __restrict__ enorm,
    const float* __restrict__ dinv, const float* __restrict__ bias,
    float* __restrict__ out, int relu) {
    int wave = (blockIdx.x * blockDim.x + threadIdx.x) >> 6;
    int lane = threadIdx.x & 63;
    if (wave >= N_NODES) return;
    int i = wave;
    float di = dinv[i];
    float selfw = di * di;
    float a0 = selfw * h[(size_t)i * 128 + lane];
    float a1 = selfw * h[(size_t)i * 128 + 64 + lane];
    int beg = colptr[i], end = colptr[i + 1];
    for (int e = beg; e < end; e++) {
        int r = erow[e];
        float w = enorm[e];
        a0 += w * h[(size_t)r * 128 + lane];
        a1 += w * h[(size_t)r * 128 + 64 + lane];
    }
    a0 += bias[lane];
    a1 += bias[64 + lane];
    if (relu) { a0 = fmaxf(a0, 0.f); a1 = fmaxf(a1, 0.f); }
    out[(size_t)i * 128 + lane] = a0;
    out[(size_t)i * 128 + 64 + lane] = a1;
}

// ---------------------------------------------------------------------------
// BatchNorm stats: per-block partials (no atomics), then small reduce.
#define BN_BLOCKS ((N_NODES + 255) / 256)

__global__ __launch_bounds__(256) void k_bnstats(const float* __restrict__ x,
                                                 float* __restrict__ psum,
                                                 float* __restrict__ psumsq) {
    int c = threadIdx.x & 127;
    int half = threadIdx.x >> 7;
    int r0 = blockIdx.x * 256;
    int rend = min(r0 + 256, N_NODES);
    float s = 0.f, s2 = 0.f;
    for (int r = r0 + half; r < rend; r += 2) {
        float v = x[(size_t)r * 128 + c];
        s += v;
        s2 += v * v;
    }
    __shared__ float sh[256], sh2[256];
    sh[threadIdx.x] = s;
    sh2[threadIdx.x] = s2;
    __syncthreads();
    if (half == 0) {
        psum[blockIdx.x * 128 + c] = sh[threadIdx.x] + sh[threadIdx.x + 128];
        psumsq[blockIdx.x * 128 + c] = sh2[threadIdx.x] + sh2[threadIdx.x + 128];
    }
}

__global__ void k_bnfinal(const float* __restrict__ psum, const float* __restrict__ psumsq,
                          const float* __restrict__ g, const float* __restrict__ be,
                          float* __restrict__ scale, float* __restrict__ shift) {
    int c = threadIdx.x;
    if (c < 128) {
        float s = 0.f, s2 = 0.f;
        for (int b = 0; b < BN_BLOCKS; b++) {
            s += psum[b * 128 + c];
            s2 += psumsq[b * 128 + c];
        }
        const float invn = 1.0f / (float)N_NODES;
        float mu = s * invn;
        float var = s2 * invn - mu * mu;
        float iv = rsqrtf(var + BN_EPS);
        float sc = g[c] * iv;
        scale[c] = sc;
        shift[c] = be[c] - mu * sc;
    }
}

// ---------------------------------------------------------------------------
// Head with fused layer-3 BN apply: x3 = a*scale+shift (written to d_out),
// logits = x3 @ linW + linb, probs = softmax(logits). 64 nodes/block.
__global__ __launch_bounds__(256) void k_logits(const float* __restrict__ abuf,
                                                const float* __restrict__ scale,
                                                const float* __restrict__ shift,
                                                const float* __restrict__ linW,
                                                const float* __restrict__ linb,
                                                float* __restrict__ logits,
                                                float* __restrict__ probs,
                                                float* __restrict__ x3out) {
    __shared__ float Xs[64][129];
    __shared__ float Ws[128 * 40];
    __shared__ float s_sc[128], s_sh[128];
    int tid = threadIdx.x;
    int m0 = blockIdx.x * 64;
    if (tid < 128) { s_sc[tid] = scale[tid]; s_sh[tid] = shift[tid]; }
    for (int q = tid; q < 1280; q += 256)
        *(float4*)&Ws[q * 4] = *(const float4*)&linW[q * 4];
    __syncthreads();
    for (int q = tid; q < 2048; q += 256) {
        int r = q >> 5, cf = (q & 31) << 2;
        float4 v = make_float4(0.f, 0.f, 0.f, 0.f);
        int m = m0 + r;
        if (m < N_NODES) {
            v = *(const float4*)&abuf[(size_t)m * 128 + cf];
            v.x = v.x * s_sc[cf + 0] + s_sh[cf + 0];
            v.y = v.y * s_sc[cf + 1] + s_sh[cf + 1];
            v.z = v.z * s_sc[cf + 2] + s_sh[cf + 2];
            v.w = v.w * s_sc[cf + 3] + s_sh[cf + 3];
            *(float4*)&x3out[(size_t)m * 128 + cf] = v;
        }
        *(float4*)&Xs[r][cf] = v;
    }
    __syncthreads();
    int r = tid >> 2;
    int cg = tid & 3;
    int cbase = cg * 10;
    float acc[10] = {};
    for (int k = 0; k < 128; k++) {
        float a = Xs[r][k];
#pragma unroll
        for (int j = 0; j < 10; j++) acc[j] += a * Ws[k * 40 + cbase + j];
    }
#pragma unroll
    for (int j = 0; j < 10; j++) acc[j] += linb[cbase + j];
    float m = acc[0];
#pragma unroll
    for (int j = 1; j < 10; j++) m = fmaxf(m, acc[j]);
    m = fmaxf(m, __shfl_xor(m, 1));
    m = fmaxf(m, __shfl_xor(m, 2));
    float ex[10];
    float s = 0.f;
#pragma unroll
    for (int j = 0; j < 10; j++) { ex[j] = expf(acc[j] - m); s += ex[j]; }
    s += __shfl_xor(s, 1);
    s += __shfl_xor(s, 2);
    float inv = 1.0f / s;
    int mrow = m0 + r;
    if (mrow < N_NODES) {
#pragma unroll
        for (int j = 0; j < 10; j++) {
            logits[(size_t)mrow * 40 + cbase + j] = acc[j];
            probs[(size_t)mrow * 40 + cbase + j] = ex[j] * inv;
        }
    }
}

// ---------------------------------------------------------------------------
extern "C" void kernel_launch(void* const* d_in, const int* in_sizes, int n_in,
                              void* d_out, int out_size, void* d_ws, size_t ws_size,
                              hipStream_t stream) {
    const float* x = (const float*)d_in[0];
    const unsigned int* eidx = (const unsigned int*)d_in[1];
    const float* ew = (const float*)d_in[2];
    const float* W1 = (const float*)d_in[3];
    const float* b1 = (const float*)d_in[4];
    const float* W2 = (const float*)d_in[5];
    const float* b2 = (const float*)d_in[6];
    const float* W3 = (const float*)d_in[7];
    const float* b3 = (const float*)d_in[8];
    const float* g1 = (const float*)d_in[9];
    const float* be1 = (const float*)d_in[10];
    const float* g2 = (const float*)d_in[11];
    const float* be2 = (const float*)d_in[12];
    const float* g3 = (const float*)d_in[13];
    const float* be3 = (const float*)d_in[14];
    const float* linW = (const float*)d_in[15];
    const float* linb = (const float*)d_in[16];

    float* out = (float*)d_out;
    float* logits = out;
    float* probs = out + (size_t)N_NODES * NCLASS;
    float* x3out = out + 2 * (size_t)N_NODES * NCLASS;

    char* ws = (char*)d_ws;
    size_t off = 0;
    auto take = [&](size_t bytes) -> char* {
        char* p = ws + off;
        off += (bytes + 255) & ~(size_t)255;
        return p;
    };
    int* row32 = (int*)take((size_t)N_EDGES * 4);
    int* col32 = (int*)take((size_t)N_EDGES * 4);
    int* colptr = (int*)take((size_t)(N_NODES + 1) * 4);
    int* cursor = (int*)take((size_t)N_NODES * 4);
    int* counts = (int*)take((size_t)N_NODES * 4);
    int* erow = (int*)take((size_t)N_EDGES * 4);
    float* enorm = (float*)take((size_t)N_EDGES * 4);
    float* deg = (float*)take((size_t)N_NODES * 4);
    float* dinv = (float*)take((size_t)N_NODES * 4);
    float* hbuf = (float*)take((size_t)N_NODES * NHID * 4);
    float* abuf = (float*)take((size_t)N_NODES * NHID * 4);
    unsigned short* W1t = (unsigned short*)take((size_t)512 * 128 * 2);
    unsigned short* W2t = (unsigned short*)take((size_t)128 * 128 * 2);
    unsigned short* W3t = (unsigned short*)take((size_t)128 * 128 * 2);
    float* psum = (float*)take((size_t)BN_BLOCKS * 128 * 4);
    float* psumsq = (float*)take((size_t)BN_BLOCKS * 128 * 4);
    float* scale = (float*)take(128 * 4);
    float* shift = (float*)take(128 * 4);
    int* flag = (int*)take(4);
    (void)ws_size; (void)n_in; (void)in_sizes; (void)out_size;

    const int TPB = 256;
    int grid_e = (N_EDGES + TPB - 1) / TPB;
    int grid_n = (N_NODES + TPB - 1) / TPB;
    int grid_gemm = (N_NODES + 127) / 128;        // 391
    int grid_agg = (N_NODES * 64) / TPB;          // 12500
    int grid_head = (N_NODES + 63) / 64;          // 782

    // graph preprocessing
    k_detect<<<1, 256, 0, stream>>>(eidx, flag);
    k_convert<<<(2 * N_EDGES + TPB - 1) / TPB, TPB, 0, stream>>>(eidx, flag, row32, col32);
    k_init_node<<<grid_n, TPB, 0, stream>>>(deg, counts);
    k_accum<<<grid_e, TPB, 0, stream>>>(col32, ew, deg, counts);
    k_dinv<<<grid_n, TPB, 0, stream>>>(deg, dinv);
    k_scan<<<1, 256, 0, stream>>>(counts, colptr, cursor);
    k_scatter<<<grid_e, TPB, 0, stream>>>(row32, col32, ew, dinv, cursor, erow, enorm);
    k_prep_w<<<(98304 + TPB - 1) / TPB, TPB, 0, stream>>>(W1, W2, W3, W1t, W2t, W3t);

    // layer 1
    k_gemm_bf16<NFEAT, false><<<grid_gemm, TPB, 0, stream>>>(x, W1t, nullptr, nullptr, hbuf, N_NODES);
    k_aggregate<<<grid_agg, TPB, 0, stream>>>(hbuf, colptr, erow, enorm, dinv, b1, abuf, 1);
    k_bnstats<<<BN_BLOCKS, TPB, 0, stream>>>(abuf, psum, psumsq);
    k_bnfinal<<<1, 128, 0, stream>>>(psum, psumsq, g1, be1, scale, shift);

    // layer 2 (BN1 apply fused into GEMM A-staging)
    k_gemm_bf16<NHID, true><<<grid_gemm, TPB, 0, stream>>>(abuf, W2t, scale, shift, hbuf, N_NODES);
    k_aggregate<<<grid_agg, TPB, 0, stream>>>(hbuf, colptr, erow, enorm, dinv, b2, abuf, 1);
    k_bnstats<<<BN_BLOCKS, TPB, 0, stream>>>(abuf, psum, psumsq);
    k_bnfinal<<<1, 128, 0, stream>>>(psum, psumsq, g2, be2, scale, shift);

    // layer 3 (BN2 apply fused into GEMM; no relu on aggregate)
    k_gemm_bf16<NHID, true><<<grid_gemm, TPB, 0, stream>>>(abuf, W3t, scale, shift, hbuf, N_NODES);
    k_aggregate<<<grid_agg, TPB, 0, stream>>>(hbuf, colptr, erow, enorm, dinv, b3, abuf, 0);
    k_bnstats<<<BN_BLOCKS, TPB, 0, stream>>>(abuf, psum, psumsq);
    k_bnfinal<<<1, 128, 0, stream>>>(psum, psumsq, g3, be3, scale, shift);

    // head: BN3 apply + x3 write + logits + softmax, all fused
    k_logits<<<grid_head, TPB, 0, stream>>>(abuf, scale, shift, linW, linb, logits, probs, x3out);
}

// Round 3
// 783.812 us; speedup vs baseline: 1.2930x; 1.1347x over previous
//
#include <hip/hip_runtime.h>
#include <hip/hip_bf16.h>

#define N_NODES 50000
#define N_EDGES 800000
#define NFEAT 512
#define NHID 128
#define NCLASS 40
#define BN_EPS 1e-5f

typedef __attribute__((ext_vector_type(8))) short short8;
typedef __attribute__((ext_vector_type(4))) float f32x4;

__device__ __forceinline__ unsigned short f2b(float f) {
    unsigned int u = __float_as_uint(f);
    u += 0x7fff + ((u >> 16) & 1);   // RTNE
    return (unsigned short)(u >> 16);
}

// ---------------------------------------------------------------------------
// Edge-index dtype detection (int64 ref layout vs int32 handed by harness).
__global__ void k_detect(const unsigned int* __restrict__ words, int* __restrict__ flag) {
    __shared__ int s_any;
    if (threadIdx.x == 0) s_any = 0;
    __syncthreads();
    unsigned int v = words[2 * threadIdx.x + 1];
    if (v != 0) atomicAdd(&s_any, 1);
    __syncthreads();
    if (threadIdx.x == 0) *flag = (s_any == 0) ? 1 : 0;  // 1 => int64 layout
}

__global__ void k_convert(const unsigned int* __restrict__ words, const int* __restrict__ flag,
                          int* __restrict__ row, int* __restrict__ col) {
    int i = blockIdx.x * blockDim.x + threadIdx.x;
    if (i >= 2 * N_EDGES) return;
    int f = *flag;
    unsigned int v = f ? words[2 * (size_t)i] : words[i];
    if (i < N_EDGES) row[i] = (int)v;
    else             col[i - N_EDGES] = (int)v;
}

// ---------------------------------------------------------------------------
__global__ void k_init_node(float* __restrict__ deg, int* __restrict__ counts) {
    int i = blockIdx.x * blockDim.x + threadIdx.x;
    if (i < N_NODES) { deg[i] = 1.0f; counts[i] = 0; }
}

__global__ void k_accum(const int* __restrict__ col, const float* __restrict__ ew,
                        float* __restrict__ deg, int* __restrict__ counts) {
    int e = blockIdx.x * blockDim.x + threadIdx.x;
    if (e < N_EDGES) {
        int c = col[e];
        atomicAdd(&deg[c], ew[e]);
        atomicAdd(&counts[c], 1);
    }
}

__global__ void k_dinv(const float* __restrict__ deg, float* __restrict__ dinv) {
    int i = blockIdx.x * blockDim.x + threadIdx.x;
    if (i < N_NODES) dinv[i] = rsqrtf(fmaxf(deg[i], 1e-30f));
}

// ---------------------------------------------------------------------------
// 3-phase parallel exclusive scan of counts[N_NODES] -> colptr/cursor.
#define SCAN_BLOCKS ((N_NODES + 255) / 256)   // 196

__global__ __launch_bounds__(256) void k_scan1(const int* __restrict__ counts,
                                               int* __restrict__ bsum) {
    int i = blockIdx.x * 256 + threadIdx.x;
    int v = (i < N_NODES) ? counts[i] : 0;
    __shared__ int sh[256];
    sh[threadIdx.x] = v;
    __syncthreads();
    for (int ofs = 128; ofs > 0; ofs >>= 1) {
        if (threadIdx.x < ofs) sh[threadIdx.x] += sh[threadIdx.x + ofs];
        __syncthreads();
    }
    if (threadIdx.x == 0) bsum[blockIdx.x] = sh[0];
}

__global__ __launch_bounds__(256) void k_scan2(const int* __restrict__ bsum,
                                               int* __restrict__ bpre,
                                               int* __restrict__ colptr) {
    int t = threadIdx.x;
    int v = (t < SCAN_BLOCKS) ? bsum[t] : 0;
    __shared__ int sh[256];
    sh[t] = v;
    __syncthreads();
    for (int ofs = 1; ofs < 256; ofs <<= 1) {
        int u = (t >= ofs) ? sh[t - ofs] : 0;
        __syncthreads();
        sh[t] += u;
        __syncthreads();
    }
    if (t < SCAN_BLOCKS) bpre[t] = sh[t] - v;  // exclusive
    if (t == SCAN_BLOCKS - 1) colptr[N_NODES] = sh[t];
}

__global__ __launch_bounds__(256) void k_scan3(const int* __restrict__ counts,
                                               const int* __restrict__ bpre,
                                               int* __restrict__ colptr,
                                               int* __restrict__ cursor) {
    int t = threadIdx.x;
    int i = blockIdx.x * 256 + t;
    int v = (i < N_NODES) ? counts[i] : 0;
    __shared__ int sh[256];
    sh[t] = v;
    __syncthreads();
    for (int ofs = 1; ofs < 256; ofs <<= 1) {
        int u = (t >= ofs) ? sh[t - ofs] : 0;
        __syncthreads();
        sh[t] += u;
        __syncthreads();
    }
    if (i < N_NODES) {
        int excl = bpre[blockIdx.x] + sh[t] - v;
        colptr[i] = excl;
        cursor[i] = excl;
    }
}

__global__ void k_scatter(const int* __restrict__ row, const int* __restrict__ col,
                          const float* __restrict__ ew, const float* __restrict__ dinv,
                          int* __restrict__ cursor, int* __restrict__ erow,
                          float* __restrict__ enorm) {
    int e = blockIdx.x * blockDim.x + threadIdx.x;
    if (e < N_EDGES) {
        int c = col[e], r = row[e];
        int p = atomicAdd(&cursor[c], 1);
        erow[p] = r;
        enorm[p] = dinv[r] * ew[e] * dinv[c];
    }
}

// ---------------------------------------------------------------------------
// Weight prep: fp32 W[K][128] -> bf16 W^T[128][K], for W1,W2,W3.
__global__ void k_prep_w(const float* __restrict__ W1, const float* __restrict__ W2,
                         const float* __restrict__ W3, unsigned short* __restrict__ W1t,
                         unsigned short* __restrict__ W2t, unsigned short* __restrict__ W3t) {
    int i = blockIdx.x * blockDim.x + threadIdx.x;
    if (i < 65536) {
        int k = i >> 7, n = i & 127;
        W1t[n * 512 + k] = f2b(W1[i]);
    } else if (i < 81920) {
        int j = i - 65536; int k = j >> 7, n = j & 127;
        W2t[n * 128 + k] = f2b(W2[j]);
    } else if (i < 98304) {
        int j = i - 81920; int k = j >> 7, n = j & 127;
        W3t[n * 128 + k] = f2b(W3[j]);
    }
}

// ---------------------------------------------------------------------------
// bf16 MFMA GEMM: Out[M,128] = A[M,K] @ W[K,128]. BM=128, BN=128, BK=32.
template <int K, bool FUSE>
__global__ __launch_bounds__(256) void k_gemm_bf16(
    const float* __restrict__ A, const unsigned short* __restrict__ Wt,
    const float* __restrict__ scale, const float* __restrict__ shift,
    float* __restrict__ Out, int M) {
    __shared__ unsigned short As[128][40];
    __shared__ unsigned short Bs[128][40];
    __shared__ float s_sc[128], s_sh[128];
    int tid = threadIdx.x;
    int m0 = blockIdx.x * 128;
    if (FUSE) {
        if (tid < 128) { s_sc[tid] = scale[tid]; s_sh[tid] = shift[tid]; }
        __syncthreads();
    }
    int srow = tid >> 1;        // 0..127
    int skh = (tid & 1) << 4;   // 0 or 16
    int wave = tid >> 6, lane = tid & 63;
    int wm = (wave >> 1) * 64, wn = (wave & 1) * 64;
    int l15 = lane & 15, quad = lane >> 4;
    f32x4 acc[4][4] = {};
    bool arow_ok = (m0 + srow) < M;
    const float* arow_p = A + (size_t)(m0 + srow) * K + skh;
    const unsigned short* wrow_p = Wt + (size_t)srow * K + skh;
    for (int kt = 0; kt < K; kt += 32) {
        float v[16];
#pragma unroll
        for (int q = 0; q < 4; q++) {
            float4 t4 = make_float4(0.f, 0.f, 0.f, 0.f);
            if (arow_ok) t4 = *(const float4*)(arow_p + kt + q * 4);
            v[q * 4 + 0] = t4.x; v[q * 4 + 1] = t4.y;
            v[q * 4 + 2] = t4.z; v[q * 4 + 3] = t4.w;
        }
        if (FUSE) {
#pragma unroll
            for (int q = 0; q < 16; q++)
                v[q] = v[q] * s_sc[kt + skh + q] + s_sh[kt + skh + q];
        }
        unsigned int p[8];
#pragma unroll
        for (int q = 0; q < 8; q++)
            p[q] = (unsigned int)f2b(v[2 * q]) | ((unsigned int)f2b(v[2 * q + 1]) << 16);
        uint4 w0 = make_uint4(p[0], p[1], p[2], p[3]);
        uint4 w1 = make_uint4(p[4], p[5], p[6], p[7]);
        uint4 b0 = *(const uint4*)(wrow_p + kt);
        uint4 b1 = *(const uint4*)(wrow_p + kt + 8);
        *(uint4*)&As[srow][skh] = w0;
        *(uint4*)&As[srow][skh + 8] = w1;
        *(uint4*)&Bs[srow][skh] = b0;
        *(uint4*)&Bs[srow][skh + 8] = b1;
        __syncthreads();
        short8 a[4], b[4];
#pragma unroll
        for (int i = 0; i < 4; i++) a[i] = *(const short8*)&As[wm + i * 16 + l15][quad * 8];
#pragma unroll
        for (int j = 0; j < 4; j++) b[j] = *(const short8*)&Bs[wn + j * 16 + l15][quad * 8];
#pragma unroll
        for (int i = 0; i < 4; i++)
#pragma unroll
            for (int j = 0; j < 4; j++)
                acc[i][j] = __builtin_amdgcn_mfma_f32_16x16x32_bf16(a[i], b[j], acc[i][j], 0, 0, 0);
        __syncthreads();
    }
#pragma unroll
    for (int i = 0; i < 4; i++) {
        int mb = m0 + wm + i * 16 + quad * 4;
#pragma unroll
        for (int r = 0; r < 4; r++) {
            int m = mb + r;
            if (m < M) {
#pragma unroll
                for (int j = 0; j < 4; j++)
                    Out[(size_t)m * 128 + wn + j * 16 + l15] = acc[i][j][r];
            }
        }
    }
}

// ---------------------------------------------------------------------------
// CSR aggregation (fp32 exact): one wave per node.
__global__ __launch_bounds__(256) void k_aggregate(
    const float* __restrict__ h, const int* __restrict__ colptr,
    const int* __restrict__ erow, const float* __restrict__ enorm,
    const float* __restrict__ dinv, const float* __restrict__ bias,
    float* __restrict__ out, int relu) {
    int wave = (blockIdx.x * blockDim.x + threadIdx.x) >> 6;
    int lane = threadIdx.x & 63;
    if (wave >= N_NODES) return;
    int i = wave;
    float di = dinv[i];
    float selfw = di * di;
    float a0 = selfw * h[(size_t)i * 128 + lane];
    float a1 = selfw * h[(size_t)i * 128 + 64 + lane];
    int beg = colptr[i], end = colptr[i + 1];
    for (int e = beg; e < end; e++) {
        int r = erow[e];
        float w = enorm[e];
        a0 += w * h[(size_t)r * 128 + lane];
        a1 += w * h[(size_t)r * 128 + 64 + lane];
    }
    a0 += bias[lane];
    a1 += bias[64 + lane];
    if (relu) { a0 = fmaxf(a0, 0.f); a1 = fmaxf(a1, 0.f); }
    out[(size_t)i * 128 + lane] = a0;
    out[(size_t)i * 128 + 64 + lane] = a1;
}

// ---------------------------------------------------------------------------
// BatchNorm stats: per-block partials (no atomics), then small reduce.
#define BN_BLOCKS ((N_NODES + 255) / 256)

__global__ __launch_bounds__(256) void k_bnstats(const float* __restrict__ x,
                                                 float* __restrict__ psum,
                                                 float* __restrict__ psumsq) {
    int c = threadIdx.x & 127;
    int half = threadIdx.x >> 7;
    int r0 = blockIdx.x * 256;
    int rend = min(r0 + 256, N_NODES);
    float s = 0.f, s2 = 0.f;
    for (int r = r0 + half; r < rend; r += 2) {
        float v = x[(size_t)r * 128 + c];
        s += v;
        s2 += v * v;
    }
    __shared__ float sh[256], sh2[256];
    sh[threadIdx.x] = s;
    sh2[threadIdx.x] = s2;
    __syncthreads();
    if (half == 0) {
        psum[blockIdx.x * 128 + c] = sh[threadIdx.x] + sh[threadIdx.x + 128];
        psumsq[blockIdx.x * 128 + c] = sh2[threadIdx.x] + sh2[threadIdx.x + 128];
    }
}

__global__ void k_bnfinal(const float* __restrict__ psum, const float* __restrict__ psumsq,
                          const float* __restrict__ g, const float* __restrict__ be,
                          float* __restrict__ scale, float* __restrict__ shift) {
    int c = threadIdx.x;
    if (c < 128) {
        float s = 0.f, s2 = 0.f;
        for (int b = 0; b < BN_BLOCKS; b++) {
            s += psum[b * 128 + c];
            s2 += psumsq[b * 128 + c];
        }
        const float invn = 1.0f / (float)N_NODES;
        float mu = s * invn;
        float var = s2 * invn - mu * mu;
        float iv = rsqrtf(var + BN_EPS);
        float sc = g[c] * iv;
        scale[c] = sc;
        shift[c] = be[c] - mu * sc;
    }
}

// ---------------------------------------------------------------------------
// Head with fused layer-3 BN apply.
__global__ __launch_bounds__(256) void k_logits(const float* __restrict__ abuf,
                                                const float* __restrict__ scale,
                                                const float* __restrict__ shift,
                                                const float* __restrict__ linW,
                                                const float* __restrict__ linb,
                                                float* __restrict__ logits,
                                                float* __restrict__ probs,
                                                float* __restrict__ x3out) {
    __shared__ float Xs[64][129];
    __shared__ float Ws[128 * 40];
    __shared__ float s_sc[128], s_sh[128];
    int tid = threadIdx.x;
    int m0 = blockIdx.x * 64;
    if (tid < 128) { s_sc[tid] = scale[tid]; s_sh[tid] = shift[tid]; }
    for (int q = tid; q < 1280; q += 256)
        *(float4*)&Ws[q * 4] = *(const float4*)&linW[q * 4];
    __syncthreads();
    for (int q = tid; q < 2048; q += 256) {
        int r = q >> 5, cf = (q & 31) << 2;
        float4 v = make_float4(0.f, 0.f, 0.f, 0.f);
        int m = m0 + r;
        if (m < N_NODES) {
            v = *(const float4*)&abuf[(size_t)m * 128 + cf];
            v.x = v.x * s_sc[cf + 0] + s_sh[cf + 0];
            v.y = v.y * s_sc[cf + 1] + s_sh[cf + 1];
            v.z = v.z * s_sc[cf + 2] + s_sh[cf + 2];
            v.w = v.w * s_sc[cf + 3] + s_sh[cf + 3];
            *(float4*)&x3out[(size_t)m * 128 + cf] = v;
        }
        *(float4*)&Xs[r][cf] = v;
    }
    __syncthreads();
    int r = tid >> 2;
    int cg = tid & 3;
    int cbase = cg * 10;
    float acc[10] = {};
    for (int k = 0; k < 128; k++) {
        float a = Xs[r][k];
#pragma unroll
        for (int j = 0; j < 10; j++) acc[j] += a * Ws[k * 40 + cbase + j];
    }
#pragma unroll
    for (int j = 0; j < 10; j++) acc[j] += linb[cbase + j];
    float m = acc[0];
#pragma unroll
    for (int j = 1; j < 10; j++) m = fmaxf(m, acc[j]);
    m = fmaxf(m, __shfl_xor(m, 1));
    m = fmaxf(m, __shfl_xor(m, 2));
    float ex[10];
    float s = 0.f;
#pragma unroll
    for (int j = 0; j < 10; j++) { ex[j] = expf(acc[j] - m); s += ex[j]; }
    s += __shfl_xor(s, 1);
    s += __shfl_xor(s, 2);
    float inv = 1.0f / s;
    int mrow = m0 + r;
    if (mrow < N_NODES) {
#pragma unroll
        for (int j = 0; j < 10; j++) {
            logits[(size_t)mrow * 40 + cbase + j] = acc[j];
            probs[(size_t)mrow * 40 + cbase + j] = ex[j] * inv;
        }
    }
}

// ---------------------------------------------------------------------------
extern "C" void kernel_launch(void* const* d_in, const int* in_sizes, int n_in,
                              void* d_out, int out_size, void* d_ws, size_t ws_size,
                              hipStream_t stream) {
    const float* x = (const float*)d_in[0];
    const unsigned int* eidx = (const unsigned int*)d_in[1];
    const float* ew = (const float*)d_in[2];
    const float* W1 = (const float*)d_in[3];
    const float* b1 = (const float*)d_in[4];
    const float* W2 = (const float*)d_in[5];
    const float* b2 = (const float*)d_in[6];
    const float* W3 = (const float*)d_in[7];
    const float* b3 = (const float*)d_in[8];
    const float* g1 = (const float*)d_in[9];
    const float* be1 = (const float*)d_in[10];
    const float* g2 = (const float*)d_in[11];
    const float* be2 = (const float*)d_in[12];
    const float* g3 = (const float*)d_in[13];
    const float* be3 = (const float*)d_in[14];
    const float* linW = (const float*)d_in[15];
    const float* linb = (const float*)d_in[16];

    float* out = (float*)d_out;
    float* logits = out;
    float* probs = out + (size_t)N_NODES * NCLASS;
    float* x3out = out + 2 * (size_t)N_NODES * NCLASS;

    char* ws = (char*)d_ws;
    size_t off = 0;
    auto take = [&](size_t bytes) -> char* {
        char* p = ws + off;
        off += (bytes + 255) & ~(size_t)255;
        return p;
    };
    int* row32 = (int*)take((size_t)N_EDGES * 4);
    int* col32 = (int*)take((size_t)N_EDGES * 4);
    int* colptr = (int*)take((size_t)(N_NODES + 1) * 4);
    int* cursor = (int*)take((size_t)N_NODES * 4);
    int* counts = (int*)take((size_t)N_NODES * 4);
    int* erow = (int*)take((size_t)N_EDGES * 4);
    float* enorm = (float*)take((size_t)N_EDGES * 4);
    float* deg = (float*)take((size_t)N_NODES * 4);
    float* dinv = (float*)take((size_t)N_NODES * 4);
    float* hbuf = (float*)take((size_t)N_NODES * NHID * 4);
    float* abuf = (float*)take((size_t)N_NODES * NHID * 4);
    unsigned short* W1t = (unsigned short*)take((size_t)512 * 128 * 2);
    unsigned short* W2t = (unsigned short*)take((size_t)128 * 128 * 2);
    unsigned short* W3t = (unsigned short*)take((size_t)128 * 128 * 2);
    float* psum = (float*)take((size_t)BN_BLOCKS * 128 * 4);
    float* psumsq = (float*)take((size_t)BN_BLOCKS * 128 * 4);
    float* scale = (float*)take(128 * 4);
    float* shift = (float*)take(128 * 4);
    int* bsum = (int*)take((size_t)SCAN_BLOCKS * 4);
    int* bpre = (int*)take((size_t)SCAN_BLOCKS * 4);
    int* flag = (int*)take(4);
    (void)ws_size; (void)n_in; (void)in_sizes; (void)out_size;

    const int TPB = 256;
    int grid_e = (N_EDGES + TPB - 1) / TPB;
    int grid_n = (N_NODES + TPB - 1) / TPB;
    int grid_gemm = (N_NODES + 127) / 128;        // 391
    int grid_agg = (N_NODES * 64) / TPB;          // 12500
    int grid_head = (N_NODES + 63) / 64;          // 782

    // graph preprocessing
    k_detect<<<1, 256, 0, stream>>>(eidx, flag);
    k_convert<<<(2 * N_EDGES + TPB - 1) / TPB, TPB, 0, stream>>>(eidx, flag, row32, col32);
    k_init_node<<<grid_n, TPB, 0, stream>>>(deg, counts);
    k_accum<<<grid_e, TPB, 0, stream>>>(col32, ew, deg, counts);
    k_dinv<<<grid_n, TPB, 0, stream>>>(deg, dinv);
    k_scan1<<<SCAN_BLOCKS, TPB, 0, stream>>>(counts, bsum);
    k_scan2<<<1, TPB, 0, stream>>>(bsum, bpre, colptr);
    k_scan3<<<SCAN_BLOCKS, TPB, 0, stream>>>(counts, bpre, colptr, cursor);
    k_scatter<<<grid_e, TPB, 0, stream>>>(row32, col32, ew, dinv, cursor, erow, enorm);
    k_prep_w<<<(98304 + TPB - 1) / TPB, TPB, 0, stream>>>(W1, W2, W3, W1t, W2t, W3t);

    // layer 1
    k_gemm_bf16<NFEAT, false><<<grid_gemm, TPB, 0, stream>>>(x, W1t, nullptr, nullptr, hbuf, N_NODES);
    k_aggregate<<<grid_agg, TPB, 0, stream>>>(hbuf, colptr, erow, enorm, dinv, b1, abuf, 1);
    k_bnstats<<<BN_BLOCKS, TPB, 0, stream>>>(abuf, psum, psumsq);
    k_bnfinal<<<1, 128, 0, stream>>>(psum, psumsq, g1, be1, scale, shift);

    // layer 2 (BN1 apply fused into GEMM A-staging)
    k_gemm_bf16<NHID, true><<<grid_gemm, TPB, 0, stream>>>(abuf, W2t, scale, shift, hbuf, N_NODES);
    k_aggregate<<<grid_agg, TPB, 0, stream>>>(hbuf, colptr, erow, enorm, dinv, b2, abuf, 1);
    k_bnstats<<<BN_BLOCKS, TPB, 0, stream>>>(abuf, psum, psumsq);
    k_bnfinal<<<1, 128, 0, stream>>>(psum, psumsq, g2, be2, scale, shift);

    // layer 3 (BN2 apply fused into GEMM; no relu on aggregate)
    k_gemm_bf16<NHID, true><<<grid_gemm, TPB, 0, stream>>>(abuf, W3t, scale, shift, hbuf, N_NODES);
    k_aggregate<<<grid_agg, TPB, 0, stream>>>(hbuf, colptr, erow, enorm, dinv, b3, abuf, 0);
    k_bnstats<<<BN_BLOCKS, TPB, 0, stream>>>(abuf, psum, psumsq);
    k_bnfinal<<<1, 128, 0, stream>>>(psum, psumsq, g3, be3, scale, shift);

    // head: BN3 apply + x3 write + logits + softmax, all fused
    k_logits<<<grid_head, TPB, 0, stream>>>(abuf, scale, shift, linW, linb, logits, probs, x3out);
}

// Round 4
// 641.712 us; speedup vs baseline: 1.5794x; 1.2214x over previous
//
#include <hip/hip_runtime.h>
#include <hip/hip_bf16.h>

#define N_NODES 50000
#define N_EDGES 800000
#define NFEAT 512
#define NHID 128
#define NCLASS 40
#define BN_EPS 1e-5f

typedef __attribute__((ext_vector_type(8))) short short8;
typedef __attribute__((ext_vector_type(4))) float f32x4;

__device__ __forceinline__ unsigned short f2b(float f) {
    unsigned int u = __float_as_uint(f);
    u += 0x7fff + ((u >> 16) & 1);   // RTNE
    return (unsigned short)(u >> 16);
}
__device__ __forceinline__ float blo(unsigned int v) {
    return __uint_as_float(v << 16);
}
__device__ __forceinline__ float bhi(unsigned int v) {
    return __uint_as_float(v & 0xffff0000u);
}

// ---------------------------------------------------------------------------
// Edge-index dtype detection (int64 ref layout vs int32 handed by harness).
__global__ void k_detect(const unsigned int* __restrict__ words, int* __restrict__ flag) {
    __shared__ int s_any;
    if (threadIdx.x == 0) s_any = 0;
    __syncthreads();
    unsigned int v = words[2 * threadIdx.x + 1];
    if (v != 0) atomicAdd(&s_any, 1);
    __syncthreads();
    if (threadIdx.x == 0) *flag = (s_any == 0) ? 1 : 0;  // 1 => int64 layout
}

__global__ void k_convert(const unsigned int* __restrict__ words, const int* __restrict__ flag,
                          int* __restrict__ row, int* __restrict__ col) {
    int i = blockIdx.x * blockDim.x + threadIdx.x;
    if (i >= 2 * N_EDGES) return;
    int f = *flag;
    unsigned int v = f ? words[2 * (size_t)i] : words[i];
    if (i < N_EDGES) row[i] = (int)v;
    else             col[i - N_EDGES] = (int)v;
}

// ---------------------------------------------------------------------------
__global__ void k_init_node(float* __restrict__ deg, int* __restrict__ counts) {
    int i = blockIdx.x * blockDim.x + threadIdx.x;
    if (i < N_NODES) { deg[i] = 1.0f; counts[i] = 0; }
}

__global__ void k_accum(const int* __restrict__ col, const float* __restrict__ ew,
                        float* __restrict__ deg, int* __restrict__ counts) {
    int e = blockIdx.x * blockDim.x + threadIdx.x;
    if (e < N_EDGES) {
        int c = col[e];
        atomicAdd(&deg[c], ew[e]);
        atomicAdd(&counts[c], 1);
    }
}

__global__ void k_dinv(const float* __restrict__ deg, float* __restrict__ dinv) {
    int i = blockIdx.x * blockDim.x + threadIdx.x;
    if (i < N_NODES) dinv[i] = rsqrtf(fmaxf(deg[i], 1e-30f));
}

// ---------------------------------------------------------------------------
// 3-phase parallel exclusive scan of counts[N_NODES] -> colptr/cursor.
#define SCAN_BLOCKS ((N_NODES + 255) / 256)   // 196

__global__ __launch_bounds__(256) void k_scan1(const int* __restrict__ counts,
                                               int* __restrict__ bsum) {
    int i = blockIdx.x * 256 + threadIdx.x;
    int v = (i < N_NODES) ? counts[i] : 0;
    __shared__ int sh[256];
    sh[threadIdx.x] = v;
    __syncthreads();
    for (int ofs = 128; ofs > 0; ofs >>= 1) {
        if (threadIdx.x < ofs) sh[threadIdx.x] += sh[threadIdx.x + ofs];
        __syncthreads();
    }
    if (threadIdx.x == 0) bsum[blockIdx.x] = sh[0];
}

__global__ __launch_bounds__(256) void k_scan2(const int* __restrict__ bsum,
                                               int* __restrict__ bpre,
                                               int* __restrict__ colptr) {
    int t = threadIdx.x;
    int v = (t < SCAN_BLOCKS) ? bsum[t] : 0;
    __shared__ int sh[256];
    sh[t] = v;
    __syncthreads();
    for (int ofs = 1; ofs < 256; ofs <<= 1) {
        int u = (t >= ofs) ? sh[t - ofs] : 0;
        __syncthreads();
        sh[t] += u;
        __syncthreads();
    }
    if (t < SCAN_BLOCKS) bpre[t] = sh[t] - v;  // exclusive
    if (t == SCAN_BLOCKS - 1) colptr[N_NODES] = sh[t];
}

__global__ __launch_bounds__(256) void k_scan3(const int* __restrict__ counts,
                                               const int* __restrict__ bpre,
                                               int* __restrict__ colptr,
                                               int* __restrict__ cursor) {
    int t = threadIdx.x;
    int i = blockIdx.x * 256 + t;
    int v = (i < N_NODES) ? counts[i] : 0;
    __shared__ int sh[256];
    sh[t] = v;
    __syncthreads();
    for (int ofs = 1; ofs < 256; ofs <<= 1) {
        int u = (t >= ofs) ? sh[t - ofs] : 0;
        __syncthreads();
        sh[t] += u;
        __syncthreads();
    }
    if (i < N_NODES) {
        int excl = bpre[blockIdx.x] + sh[t] - v;
        colptr[i] = excl;
        cursor[i] = excl;
    }
}

__global__ void k_scatter(const int* __restrict__ row, const int* __restrict__ col,
                          const float* __restrict__ ew, const float* __restrict__ dinv,
                          int* __restrict__ cursor, int* __restrict__ erow,
                          float* __restrict__ enorm) {
    int e = blockIdx.x * blockDim.x + threadIdx.x;
    if (e < N_EDGES) {
        int c = col[e], r = row[e];
        int p = atomicAdd(&cursor[c], 1);
        erow[p] = r;
        enorm[p] = dinv[r] * ew[e] * dinv[c];
    }
}

// ---------------------------------------------------------------------------
// Weight prep: fp32 W[K][128] -> bf16 W^T[128][K], for W1,W2,W3.
__global__ void k_prep_w(const float* __restrict__ W1, const float* __restrict__ W2,
                         const float* __restrict__ W3, unsigned short* __restrict__ W1t,
                         unsigned short* __restrict__ W2t, unsigned short* __restrict__ W3t) {
    int i = blockIdx.x * blockDim.x + threadIdx.x;
    if (i < 65536) {
        int k = i >> 7, n = i & 127;
        W1t[n * 512 + k] = f2b(W1[i]);
    } else if (i < 81920) {
        int j = i - 65536; int k = j >> 7, n = j & 127;
        W2t[n * 128 + k] = f2b(W2[j]);
    } else if (i < 98304) {
        int j = i - 81920; int k = j >> 7, n = j & 127;
        W3t[n * 128 + k] = f2b(W3[j]);
    }
}

// ---------------------------------------------------------------------------
// bf16 MFMA GEMM: Out[M,128](bf16) = A[M,K](fp32) @ W[K,128]. BM=128 BN=128 BK=32.
template <int K, bool FUSE>
__global__ __launch_bounds__(256) void k_gemm_bf16(
    const float* __restrict__ A, const unsigned short* __restrict__ Wt,
    const float* __restrict__ scale, const float* __restrict__ shift,
    unsigned short* __restrict__ Out, int M) {
    __shared__ unsigned short As[128][40];
    __shared__ unsigned short Bs[128][40];
    __shared__ float s_sc[128], s_sh[128];
    int tid = threadIdx.x;
    int m0 = blockIdx.x * 128;
    if (FUSE) {
        if (tid < 128) { s_sc[tid] = scale[tid]; s_sh[tid] = shift[tid]; }
        __syncthreads();
    }
    int srow = tid >> 1;        // 0..127
    int skh = (tid & 1) << 4;   // 0 or 16
    int wave = tid >> 6, lane = tid & 63;
    int wm = (wave >> 1) * 64, wn = (wave & 1) * 64;
    int l15 = lane & 15, quad = lane >> 4;
    f32x4 acc[4][4] = {};
    bool arow_ok = (m0 + srow) < M;
    const float* arow_p = A + (size_t)(m0 + srow) * K + skh;
    const unsigned short* wrow_p = Wt + (size_t)srow * K + skh;
    for (int kt = 0; kt < K; kt += 32) {
        float v[16];
#pragma unroll
        for (int q = 0; q < 4; q++) {
            float4 t4 = make_float4(0.f, 0.f, 0.f, 0.f);
            if (arow_ok) t4 = *(const float4*)(arow_p + kt + q * 4);
            v[q * 4 + 0] = t4.x; v[q * 4 + 1] = t4.y;
            v[q * 4 + 2] = t4.z; v[q * 4 + 3] = t4.w;
        }
        if (FUSE) {
#pragma unroll
            for (int q = 0; q < 16; q++)
                v[q] = v[q] * s_sc[kt + skh + q] + s_sh[kt + skh + q];
        }
        unsigned int p[8];
#pragma unroll
        for (int q = 0; q < 8; q++)
            p[q] = (unsigned int)f2b(v[2 * q]) | ((unsigned int)f2b(v[2 * q + 1]) << 16);
        uint4 w0 = make_uint4(p[0], p[1], p[2], p[3]);
        uint4 w1 = make_uint4(p[4], p[5], p[6], p[7]);
        uint4 b0 = *(const uint4*)(wrow_p + kt);
        uint4 b1 = *(const uint4*)(wrow_p + kt + 8);
        *(uint4*)&As[srow][skh] = w0;
        *(uint4*)&As[srow][skh + 8] = w1;
        *(uint4*)&Bs[srow][skh] = b0;
        *(uint4*)&Bs[srow][skh + 8] = b1;
        __syncthreads();
        short8 a[4], b[4];
#pragma unroll
        for (int i = 0; i < 4; i++) a[i] = *(const short8*)&As[wm + i * 16 + l15][quad * 8];
#pragma unroll
        for (int j = 0; j < 4; j++) b[j] = *(const short8*)&Bs[wn + j * 16 + l15][quad * 8];
#pragma unroll
        for (int i = 0; i < 4; i++)
#pragma unroll
            for (int j = 0; j < 4; j++)
                acc[i][j] = __builtin_amdgcn_mfma_f32_16x16x32_bf16(a[i], b[j], acc[i][j], 0, 0, 0);
        __syncthreads();
    }
#pragma unroll
    for (int i = 0; i < 4; i++) {
        int mb = m0 + wm + i * 16 + quad * 4;
#pragma unroll
        for (int r = 0; r < 4; r++) {
            int m = mb + r;
            if (m < M) {
#pragma unroll
                for (int j = 0; j < 4; j++)
                    Out[(size_t)m * 128 + wn + j * 16 + l15] = f2b(acc[i][j][r]);
            }
        }
    }
}

// ---------------------------------------------------------------------------
// CSR aggregation: one wave per node, h in bf16 (one uint per lane = channels
// 2l,2l+1), fp32 accumulate, 4-way unrolled gather for MLP. float2 stores.
__global__ __launch_bounds__(256) void k_aggregate(
    const unsigned int* __restrict__ hb, const int* __restrict__ colptr,
    const int* __restrict__ erow, const float* __restrict__ enorm,
    const float* __restrict__ dinv, const float* __restrict__ bias,
    float* __restrict__ out, int relu) {
    int node = (blockIdx.x * blockDim.x + threadIdx.x) >> 6;
    int lane = threadIdx.x & 63;
    if (node >= N_NODES) return;
    float di = dinv[node];
    float selfw = di * di;
    unsigned int sv = hb[(size_t)node * 64 + lane];
    float a0 = selfw * blo(sv);
    float a1 = selfw * bhi(sv);
    int e = colptr[node], end = colptr[node + 1];
    for (; e + 4 <= end; e += 4) {
        int r0 = erow[e], r1 = erow[e + 1], r2 = erow[e + 2], r3 = erow[e + 3];
        float w0 = enorm[e], w1 = enorm[e + 1], w2 = enorm[e + 2], w3 = enorm[e + 3];
        unsigned int v0 = hb[(size_t)r0 * 64 + lane];
        unsigned int v1 = hb[(size_t)r1 * 64 + lane];
        unsigned int v2 = hb[(size_t)r2 * 64 + lane];
        unsigned int v3 = hb[(size_t)r3 * 64 + lane];
        a0 += w0 * blo(v0); a1 += w0 * bhi(v0);
        a0 += w1 * blo(v1); a1 += w1 * bhi(v1);
        a0 += w2 * blo(v2); a1 += w2 * bhi(v2);
        a0 += w3 * blo(v3); a1 += w3 * bhi(v3);
    }
    for (; e < end; e++) {
        int r = erow[e];
        float w = enorm[e];
        unsigned int v = hb[(size_t)r * 64 + lane];
        a0 += w * blo(v);
        a1 += w * bhi(v);
    }
    float2 bv = *(const float2*)&bias[2 * lane];
    a0 += bv.x;
    a1 += bv.y;
    if (relu) { a0 = fmaxf(a0, 0.f); a1 = fmaxf(a1, 0.f); }
    *(float2*)&out[(size_t)node * 128 + 2 * lane] = make_float2(a0, a1);
}

// ---------------------------------------------------------------------------
// BatchNorm stats: per-block partials (no atomics), then small reduce.
#define BN_BLOCKS ((N_NODES + 255) / 256)

__global__ __launch_bounds__(256) void k_bnstats(const float* __restrict__ x,
                                                 float* __restrict__ psum,
                                                 float* __restrict__ psumsq) {
    int c = threadIdx.x & 127;
    int half = threadIdx.x >> 7;
    int r0 = blockIdx.x * 256;
    int rend = min(r0 + 256, N_NODES);
    float s = 0.f, s2 = 0.f;
    for (int r = r0 + half; r < rend; r += 2) {
        float v = x[(size_t)r * 128 + c];
        s += v;
        s2 += v * v;
    }
    __shared__ float sh[256], sh2[256];
    sh[threadIdx.x] = s;
    sh2[threadIdx.x] = s2;
    __syncthreads();
    if (half == 0) {
        psum[blockIdx.x * 128 + c] = sh[threadIdx.x] + sh[threadIdx.x + 128];
        psumsq[blockIdx.x * 128 + c] = sh2[threadIdx.x] + sh2[threadIdx.x + 128];
    }
}

__global__ void k_bnfinal(const float* __restrict__ psum, const float* __restrict__ psumsq,
                          const float* __restrict__ g, const float* __restrict__ be,
                          float* __restrict__ scale, float* __restrict__ shift) {
    int c = threadIdx.x;
    if (c < 128) {
        float s = 0.f, s2 = 0.f;
        for (int b = 0; b < BN_BLOCKS; b++) {
            s += psum[b * 128 + c];
            s2 += psumsq[b * 128 + c];
        }
        const float invn = 1.0f / (float)N_NODES;
        float mu = s * invn;
        float var = s2 * invn - mu * mu;
        float iv = rsqrtf(var + BN_EPS);
        float sc = g[c] * iv;
        scale[c] = sc;
        shift[c] = be[c] - mu * sc;
    }
}

// ---------------------------------------------------------------------------
// Head with fused layer-3 BN apply.
__global__ __launch_bounds__(256) void k_logits(const float* __restrict__ abuf,
                                                const float* __restrict__ scale,
                                                const float* __restrict__ shift,
                                                const float* __restrict__ linW,
                                                const float* __restrict__ linb,
                                                float* __restrict__ logits,
                                                float* __restrict__ probs,
                                                float* __restrict__ x3out) {
    __shared__ float Xs[64][129];
    __shared__ float Ws[128 * 40];
    __shared__ float s_sc[128], s_sh[128];
    int tid = threadIdx.x;
    int m0 = blockIdx.x * 64;
    if (tid < 128) { s_sc[tid] = scale[tid]; s_sh[tid] = shift[tid]; }
    for (int q = tid; q < 1280; q += 256)
        *(float4*)&Ws[q * 4] = *(const float4*)&linW[q * 4];
    __syncthreads();
    for (int q = tid; q < 2048; q += 256) {
        int r = q >> 5, cf = (q & 31) << 2;
        float4 v = make_float4(0.f, 0.f, 0.f, 0.f);
        int m = m0 + r;
        if (m < N_NODES) {
            v = *(const float4*)&abuf[(size_t)m * 128 + cf];
            v.x = v.x * s_sc[cf + 0] + s_sh[cf + 0];
            v.y = v.y * s_sc[cf + 1] + s_sh[cf + 1];
            v.z = v.z * s_sc[cf + 2] + s_sh[cf + 2];
            v.w = v.w * s_sc[cf + 3] + s_sh[cf + 3];
            *(float4*)&x3out[(size_t)m * 128 + cf] = v;
        }
        *(float4*)&Xs[r][cf] = v;
    }
    __syncthreads();
    int r = tid >> 2;
    int cg = tid & 3;
    int cbase = cg * 10;
    float acc[10] = {};
    for (int k = 0; k < 128; k++) {
        float a = Xs[r][k];
#pragma unroll
        for (int j = 0; j < 10; j++) acc[j] += a * Ws[k * 40 + cbase + j];
    }
#pragma unroll
    for (int j = 0; j < 10; j++) acc[j] += linb[cbase + j];
    float m = acc[0];
#pragma unroll
    for (int j = 1; j < 10; j++) m = fmaxf(m, acc[j]);
    m = fmaxf(m, __shfl_xor(m, 1));
    m = fmaxf(m, __shfl_xor(m, 2));
    float ex[10];
    float s = 0.f;
#pragma unroll
    for (int j = 0; j < 10; j++) { ex[j] = expf(acc[j] - m); s += ex[j]; }
    s += __shfl_xor(s, 1);
    s += __shfl_xor(s, 2);
    float inv = 1.0f / s;
    int mrow = m0 + r;
    if (mrow < N_NODES) {
#pragma unroll
        for (int j = 0; j < 10; j++) {
            logits[(size_t)mrow * 40 + cbase + j] = acc[j];
            probs[(size_t)mrow * 40 + cbase + j] = ex[j] * inv;
        }
    }
}

// ---------------------------------------------------------------------------
extern "C" void kernel_launch(void* const* d_in, const int* in_sizes, int n_in,
                              void* d_out, int out_size, void* d_ws, size_t ws_size,
                              hipStream_t stream) {
    const float* x = (const float*)d_in[0];
    const unsigned int* eidx = (const unsigned int*)d_in[1];
    const float* ew = (const float*)d_in[2];
    const float* W1 = (const float*)d_in[3];
    const float* b1 = (const float*)d_in[4];
    const float* W2 = (const float*)d_in[5];
    const float* b2 = (const float*)d_in[6];
    const float* W3 = (const float*)d_in[7];
    const float* b3 = (const float*)d_in[8];
    const float* g1 = (const float*)d_in[9];
    const float* be1 = (const float*)d_in[10];
    const float* g2 = (const float*)d_in[11];
    const float* be2 = (const float*)d_in[12];
    const float* g3 = (const float*)d_in[13];
    const float* be3 = (const float*)d_in[14];
    const float* linW = (const float*)d_in[15];
    const float* linb = (const float*)d_in[16];

    float* out = (float*)d_out;
    float* logits = out;
    float* probs = out + (size_t)N_NODES * NCLASS;
    float* x3out = out + 2 * (size_t)N_NODES * NCLASS;

    char* ws = (char*)d_ws;
    size_t off = 0;
    auto take = [&](size_t bytes) -> char* {
        char* p = ws + off;
        off += (bytes + 255) & ~(size_t)255;
        return p;
    };
    int* row32 = (int*)take((size_t)N_EDGES * 4);
    int* col32 = (int*)take((size_t)N_EDGES * 4);
    int* colptr = (int*)take((size_t)(N_NODES + 1) * 4);
    int* cursor = (int*)take((size_t)N_NODES * 4);
    int* counts = (int*)take((size_t)N_NODES * 4);
    int* erow = (int*)take((size_t)N_EDGES * 4);
    float* enorm = (float*)take((size_t)N_EDGES * 4);
    float* deg = (float*)take((size_t)N_NODES * 4);
    float* dinv = (float*)take((size_t)N_NODES * 4);
    unsigned short* hbuf = (unsigned short*)take((size_t)N_NODES * NHID * 2);
    float* abuf = (float*)take((size_t)N_NODES * NHID * 4);
    unsigned short* W1t = (unsigned short*)take((size_t)512 * 128 * 2);
    unsigned short* W2t = (unsigned short*)take((size_t)128 * 128 * 2);
    unsigned short* W3t = (unsigned short*)take((size_t)128 * 128 * 2);
    float* psum = (float*)take((size_t)BN_BLOCKS * 128 * 4);
    float* psumsq = (float*)take((size_t)BN_BLOCKS * 128 * 4);
    float* scale = (float*)take(128 * 4);
    float* shift = (float*)take(128 * 4);
    int* bsum = (int*)take((size_t)SCAN_BLOCKS * 4);
    int* bpre = (int*)take((size_t)SCAN_BLOCKS * 4);
    int* flag = (int*)take(4);
    (void)ws_size; (void)n_in; (void)in_sizes; (void)out_size;

    const int TPB = 256;
    int grid_e = (N_EDGES + TPB - 1) / TPB;
    int grid_n = (N_NODES + TPB - 1) / TPB;
    int grid_gemm = (N_NODES + 127) / 128;        // 391
    int grid_agg = (N_NODES * 64 + TPB - 1) / TPB;
    int grid_head = (N_NODES + 63) / 64;          // 782

    // graph preprocessing
    k_detect<<<1, 256, 0, stream>>>(eidx, flag);
    k_convert<<<(2 * N_EDGES + TPB - 1) / TPB, TPB, 0, stream>>>(eidx, flag, row32, col32);
    k_init_node<<<grid_n, TPB, 0, stream>>>(deg, counts);
    k_accum<<<grid_e, TPB, 0, stream>>>(col32, ew, deg, counts);
    k_dinv<<<grid_n, TPB, 0, stream>>>(deg, dinv);
    k_scan1<<<SCAN_BLOCKS, TPB, 0, stream>>>(counts, bsum);
    k_scan2<<<1, TPB, 0, stream>>>(bsum, bpre, colptr);
    k_scan3<<<SCAN_BLOCKS, TPB, 0, stream>>>(counts, bpre, colptr, cursor);
    k_scatter<<<grid_e, TPB, 0, stream>>>(row32, col32, ew, dinv, cursor, erow, enorm);
    k_prep_w<<<(98304 + TPB - 1) / TPB, TPB, 0, stream>>>(W1, W2, W3, W1t, W2t, W3t);

    // layer 1
    k_gemm_bf16<NFEAT, false><<<grid_gemm, TPB, 0, stream>>>(x, W1t, nullptr, nullptr, hbuf, N_NODES);
    k_aggregate<<<grid_agg, TPB, 0, stream>>>((const unsigned int*)hbuf, colptr, erow, enorm, dinv, b1, abuf, 1);
    k_bnstats<<<BN_BLOCKS, TPB, 0, stream>>>(abuf, psum, psumsq);
    k_bnfinal<<<1, 128, 0, stream>>>(psum, psumsq, g1, be1, scale, shift);

    // layer 2 (BN1 apply fused into GEMM A-staging)
    k_gemm_bf16<NHID, true><<<grid_gemm, TPB, 0, stream>>>(abuf, W2t, scale, shift, hbuf, N_NODES);
    k_aggregate<<<grid_agg, TPB, 0, stream>>>((const unsigned int*)hbuf, colptr, erow, enorm, dinv, b2, abuf, 1);
    k_bnstats<<<BN_BLOCKS, TPB, 0, stream>>>(abuf, psum, psumsq);
    k_bnfinal<<<1, 128, 0, stream>>>(psum, psumsq, g2, be2, scale, shift);

    // layer 3 (BN2 apply fused into GEMM; no relu on aggregate)
    k_gemm_bf16<NHID, true><<<grid_gemm, TPB, 0, stream>>>(abuf, W3t, scale, shift, hbuf, N_NODES);
    k_aggregate<<<grid_agg, TPB, 0, stream>>>((const unsigned int*)hbuf, colptr, erow, enorm, dinv, b3, abuf, 0);
    k_bnstats<<<BN_BLOCKS, TPB, 0, stream>>>(abuf, psum, psumsq);
    k_bnfinal<<<1, 128, 0, stream>>>(psum, psumsq, g3, be3, scale, shift);

    // head: BN3 apply + x3 write + logits + softmax, all fused
    k_logits<<<grid_head, TPB, 0, stream>>>(abuf, scale, shift, linW, linb, logits, probs, x3out);
}

// Round 5
// 579.238 us; speedup vs baseline: 1.7497x; 1.1079x over previous
//
#include <hip/hip_runtime.h>
#include <hip/hip_bf16.h>

#define N_NODES 50000
#define N_EDGES 800000
#define NFEAT 512
#define NHID 128
#define NCLASS 40
#define BN_EPS 1e-5f

typedef __attribute__((ext_vector_type(8))) short short8;
typedef __attribute__((ext_vector_type(4))) float f32x4;

__device__ __forceinline__ unsigned short f2b(float f) {
    unsigned int u = __float_as_uint(f);
    u += 0x7fff + ((u >> 16) & 1);   // RTNE
    return (unsigned short)(u >> 16);
}
__device__ __forceinline__ float blo(unsigned int v) {
    return __uint_as_float(v << 16);
}
__device__ __forceinline__ float bhi(unsigned int v) {
    return __uint_as_float(v & 0xffff0000u);
}

// ---------------------------------------------------------------------------
// Edge-index dtype detection (int64 ref layout vs int32 handed by harness).
__global__ void k_detect(const unsigned int* __restrict__ words, int* __restrict__ flag) {
    __shared__ int s_any;
    if (threadIdx.x == 0) s_any = 0;
    __syncthreads();
    unsigned int v = words[2 * threadIdx.x + 1];
    if (v != 0) atomicAdd(&s_any, 1);
    __syncthreads();
    if (threadIdx.x == 0) *flag = (s_any == 0) ? 1 : 0;  // 1 => int64 layout
}

__global__ void k_convert(const unsigned int* __restrict__ words, const int* __restrict__ flag,
                          int* __restrict__ row, int* __restrict__ col) {
    int i = blockIdx.x * blockDim.x + threadIdx.x;
    if (i >= 2 * N_EDGES) return;
    int f = *flag;
    unsigned int v = f ? words[2 * (size_t)i] : words[i];
    if (i < N_EDGES) row[i] = (int)v;
    else             col[i - N_EDGES] = (int)v;
}

// ---------------------------------------------------------------------------
__global__ void k_init_node(unsigned long long* __restrict__ degcnt) {
    int i = blockIdx.x * blockDim.x + threadIdx.x;
    if (i < N_NODES) degcnt[i] = 0ULL;
}

// One 64-bit atomic per edge: high word = count (and returns CSR slot),
// low word = fixed-point (2^23) sum of edge weights. ew in [0,1] so low-word
// overflow needs >=512 edges on one node (Binomial(800k,1/50k), mean 16 —
// probability ~0).
__global__ void k_accum(const int* __restrict__ col, const float* __restrict__ ew,
                        unsigned long long* __restrict__ degcnt, int* __restrict__ slot) {
    int e = blockIdx.x * blockDim.x + threadIdx.x;
    if (e < N_EDGES) {
        int c = col[e];
        unsigned int q = __float2uint_rn(ew[e] * 8388608.0f);  // 2^23
        unsigned long long old = atomicAdd(&degcnt[c], (1ULL << 32) | (unsigned long long)q);
        slot[e] = (int)(old >> 32);
    }
}

// deg = 1 (self loop) + fixedpoint/2^23; also extract counts for the scan.
__global__ void k_dinv(const unsigned long long* __restrict__ degcnt,
                       float* __restrict__ dinv, int* __restrict__ counts) {
    int i = blockIdx.x * blockDim.x + threadIdx.x;
    if (i < N_NODES) {
        unsigned long long v = degcnt[i];
        float deg = 1.0f + (float)(unsigned int)(v & 0xffffffffULL) * (1.0f / 8388608.0f);
        dinv[i] = rsqrtf(deg);
        counts[i] = (int)(v >> 32);
    }
}

// ---------------------------------------------------------------------------
// 3-phase parallel exclusive scan of counts[N_NODES] -> colptr.
#define SCAN_BLOCKS ((N_NODES + 255) / 256)   // 196

__global__ __launch_bounds__(256) void k_scan1(const int* __restrict__ counts,
                                               int* __restrict__ bsum) {
    int i = blockIdx.x * 256 + threadIdx.x;
    int v = (i < N_NODES) ? counts[i] : 0;
    __shared__ int sh[256];
    sh[threadIdx.x] = v;
    __syncthreads();
    for (int ofs = 128; ofs > 0; ofs >>= 1) {
        if (threadIdx.x < ofs) sh[threadIdx.x] += sh[threadIdx.x + ofs];
        __syncthreads();
    }
    if (threadIdx.x == 0) bsum[blockIdx.x] = sh[0];
}

__global__ __launch_bounds__(256) void k_scan2(const int* __restrict__ bsum,
                                               int* __restrict__ bpre,
                                               int* __restrict__ colptr) {
    int t = threadIdx.x;
    int v = (t < SCAN_BLOCKS) ? bsum[t] : 0;
    __shared__ int sh[256];
    sh[t] = v;
    __syncthreads();
    for (int ofs = 1; ofs < 256; ofs <<= 1) {
        int u = (t >= ofs) ? sh[t - ofs] : 0;
        __syncthreads();
        sh[t] += u;
        __syncthreads();
    }
    if (t < SCAN_BLOCKS) bpre[t] = sh[t] - v;  // exclusive
    if (t == SCAN_BLOCKS - 1) colptr[N_NODES] = sh[t];
}

__global__ __launch_bounds__(256) void k_scan3(const int* __restrict__ counts,
                                               const int* __restrict__ bpre,
                                               int* __restrict__ colptr) {
    int t = threadIdx.x;
    int i = blockIdx.x * 256 + t;
    int v = (i < N_NODES) ? counts[i] : 0;
    __shared__ int sh[256];
    sh[t] = v;
    __syncthreads();
    for (int ofs = 1; ofs < 256; ofs <<= 1) {
        int u = (t >= ofs) ? sh[t - ofs] : 0;
        __syncthreads();
        sh[t] += u;
        __syncthreads();
    }
    if (i < N_NODES) colptr[i] = bpre[blockIdx.x] + sh[t] - v;
}

// Atomic-free scatter: position = colptr[col] + per-node slot from k_accum.
__global__ void k_scatter(const int* __restrict__ row, const int* __restrict__ col,
                          const float* __restrict__ ew, const float* __restrict__ dinv,
                          const int* __restrict__ colptr, const int* __restrict__ slot,
                          int* __restrict__ erow, float* __restrict__ enorm) {
    int e = blockIdx.x * blockDim.x + threadIdx.x;
    if (e < N_EDGES) {
        int c = col[e], r = row[e];
        int p = colptr[c] + slot[e];
        erow[p] = r;
        enorm[p] = dinv[r] * ew[e] * dinv[c];
    }
}

// ---------------------------------------------------------------------------
// Weight prep: fp32 W[K][128] -> bf16 W^T[128][K], for W1,W2,W3.
__global__ void k_prep_w(const float* __restrict__ W1, const float* __restrict__ W2,
                         const float* __restrict__ W3, unsigned short* __restrict__ W1t,
                         unsigned short* __restrict__ W2t, unsigned short* __restrict__ W3t) {
    int i = blockIdx.x * blockDim.x + threadIdx.x;
    if (i < 65536) {
        int k = i >> 7, n = i & 127;
        W1t[n * 512 + k] = f2b(W1[i]);
    } else if (i < 81920) {
        int j = i - 65536; int k = j >> 7, n = j & 127;
        W2t[n * 128 + k] = f2b(W2[j]);
    } else if (i < 98304) {
        int j = i - 81920; int k = j >> 7, n = j & 127;
        W3t[n * 128 + k] = f2b(W3[j]);
    }
}

// ---------------------------------------------------------------------------
// bf16 MFMA GEMM: Out[M,128](bf16) = A[M,K](fp32) @ W[K,128]. BM=128 BN=128 BK=32.
template <int K, bool FUSE>
__global__ __launch_bounds__(256) void k_gemm_bf16(
    const float* __restrict__ A, const unsigned short* __restrict__ Wt,
    const float* __restrict__ scale, const float* __restrict__ shift,
    unsigned short* __restrict__ Out, int M) {
    __shared__ unsigned short As[128][40];
    __shared__ unsigned short Bs[128][40];
    __shared__ float s_sc[128], s_sh[128];
    int tid = threadIdx.x;
    int m0 = blockIdx.x * 128;
    if (FUSE) {
        if (tid < 128) { s_sc[tid] = scale[tid]; s_sh[tid] = shift[tid]; }
        __syncthreads();
    }
    int srow = tid >> 1;        // 0..127
    int skh = (tid & 1) << 4;   // 0 or 16
    int wave = tid >> 6, lane = tid & 63;
    int wm = (wave >> 1) * 64, wn = (wave & 1) * 64;
    int l15 = lane & 15, quad = lane >> 4;
    f32x4 acc[4][4] = {};
    bool arow_ok = (m0 + srow) < M;
    const float* arow_p = A + (size_t)(m0 + srow) * K + skh;
    const unsigned short* wrow_p = Wt + (size_t)srow * K + skh;
    for (int kt = 0; kt < K; kt += 32) {
        float v[16];
#pragma unroll
        for (int q = 0; q < 4; q++) {
            float4 t4 = make_float4(0.f, 0.f, 0.f, 0.f);
            if (arow_ok) t4 = *(const float4*)(arow_p + kt + q * 4);
            v[q * 4 + 0] = t4.x; v[q * 4 + 1] = t4.y;
            v[q * 4 + 2] = t4.z; v[q * 4 + 3] = t4.w;
        }
        if (FUSE) {
#pragma unroll
            for (int q = 0; q < 16; q++)
                v[q] = v[q] * s_sc[kt + skh + q] + s_sh[kt + skh + q];
        }
        unsigned int p[8];
#pragma unroll
        for (int q = 0; q < 8; q++)
            p[q] = (unsigned int)f2b(v[2 * q]) | ((unsigned int)f2b(v[2 * q + 1]) << 16);
        uint4 w0 = make_uint4(p[0], p[1], p[2], p[3]);
        uint4 w1 = make_uint4(p[4], p[5], p[6], p[7]);
        uint4 b0 = *(const uint4*)(wrow_p + kt);
        uint4 b1 = *(const uint4*)(wrow_p + kt + 8);
        *(uint4*)&As[srow][skh] = w0;
        *(uint4*)&As[srow][skh + 8] = w1;
        *(uint4*)&Bs[srow][skh] = b0;
        *(uint4*)&Bs[srow][skh + 8] = b1;
        __syncthreads();
        short8 a[4], b[4];
#pragma unroll
        for (int i = 0; i < 4; i++) a[i] = *(const short8*)&As[wm + i * 16 + l15][quad * 8];
#pragma unroll
        for (int j = 0; j < 4; j++) b[j] = *(const short8*)&Bs[wn + j * 16 + l15][quad * 8];
#pragma unroll
        for (int i = 0; i < 4; i++)
#pragma unroll
            for (int j = 0; j < 4; j++)
                acc[i][j] = __builtin_amdgcn_mfma_f32_16x16x32_bf16(a[i], b[j], acc[i][j], 0, 0, 0);
        __syncthreads();
    }
#pragma unroll
    for (int i = 0; i < 4; i++) {
        int mb = m0 + wm + i * 16 + quad * 4;
#pragma unroll
        for (int r = 0; r < 4; r++) {
            int m = mb + r;
            if (m < M) {
#pragma unroll
                for (int j = 0; j < 4; j++)
                    Out[(size_t)m * 128 + wn + j * 16 + l15] = f2b(acc[i][j][r]);
            }
        }
    }
}

// ---------------------------------------------------------------------------
// CSR aggregation: one wave per node, h in bf16 (one uint per lane = channels
// 2l,2l+1), fp32 accumulate, 4-way unrolled gather for MLP. float2 stores.
__global__ __launch_bounds__(256) void k_aggregate(
    const unsigned int* __restrict__ hb, const int* __restrict__ colptr,
    const int* __restrict__ erow, const float* __restrict__ enorm,
    const float* __restrict__ dinv, const float* __restrict__ bias,
    float* __restrict__ out, int relu) {
    int node = (blockIdx.x * blockDim.x + threadIdx.x) >> 6;
    int lane = threadIdx.x & 63;
    if (node >= N_NODES) return;
    float di = dinv[node];
    float selfw = di * di;
    unsigned int sv = hb[(size_t)node * 64 + lane];
    float a0 = selfw * blo(sv);
    float a1 = selfw * bhi(sv);
    int e = colptr[node], end = colptr[node + 1];
    for (; e + 4 <= end; e += 4) {
        int r0 = erow[e], r1 = erow[e + 1], r2 = erow[e + 2], r3 = erow[e + 3];
        float w0 = enorm[e], w1 = enorm[e + 1], w2 = enorm[e + 2], w3 = enorm[e + 3];
        unsigned int v0 = hb[(size_t)r0 * 64 + lane];
        unsigned int v1 = hb[(size_t)r1 * 64 + lane];
        unsigned int v2 = hb[(size_t)r2 * 64 + lane];
        unsigned int v3 = hb[(size_t)r3 * 64 + lane];
        a0 += w0 * blo(v0); a1 += w0 * bhi(v0);
        a0 += w1 * blo(v1); a1 += w1 * bhi(v1);
        a0 += w2 * blo(v2); a1 += w2 * bhi(v2);
        a0 += w3 * blo(v3); a1 += w3 * bhi(v3);
    }
    for (; e < end; e++) {
        int r = erow[e];
        float w = enorm[e];
        unsigned int v = hb[(size_t)r * 64 + lane];
        a0 += w * blo(v);
        a1 += w * bhi(v);
    }
    float2 bv = *(const float2*)&bias[2 * lane];
    a0 += bv.x;
    a1 += bv.y;
    if (relu) { a0 = fmaxf(a0, 0.f); a1 = fmaxf(a1, 0.f); }
    *(float2*)&out[(size_t)node * 128 + 2 * lane] = make_float2(a0, a1);
}

// ---------------------------------------------------------------------------
// BatchNorm stats: per-block partials (no atomics), then small reduce.
#define BN_BLOCKS ((N_NODES + 255) / 256)

__global__ __launch_bounds__(256) void k_bnstats(const float* __restrict__ x,
                                                 float* __restrict__ psum,
                                                 float* __restrict__ psumsq) {
    int c = threadIdx.x & 127;
    int half = threadIdx.x >> 7;
    int r0 = blockIdx.x * 256;
    int rend = min(r0 + 256, N_NODES);
    float s = 0.f, s2 = 0.f;
    for (int r = r0 + half; r < rend; r += 2) {
        float v = x[(size_t)r * 128 + c];
        s += v;
        s2 += v * v;
    }
    __shared__ float sh[256], sh2[256];
    sh[threadIdx.x] = s;
    sh2[threadIdx.x] = s2;
    __syncthreads();
    if (half == 0) {
        psum[blockIdx.x * 128 + c] = sh[threadIdx.x] + sh[threadIdx.x + 128];
        psumsq[blockIdx.x * 128 + c] = sh2[threadIdx.x] + sh2[threadIdx.x + 128];
    }
}

__global__ void k_bnfinal(const float* __restrict__ psum, const float* __restrict__ psumsq,
                          const float* __restrict__ g, const float* __restrict__ be,
                          float* __restrict__ scale, float* __restrict__ shift) {
    int c = threadIdx.x;
    if (c < 128) {
        float s = 0.f, s2 = 0.f;
        for (int b = 0; b < BN_BLOCKS; b++) {
            s += psum[b * 128 + c];
            s2 += psumsq[b * 128 + c];
        }
        const float invn = 1.0f / (float)N_NODES;
        float mu = s * invn;
        float var = s2 * invn - mu * mu;
        float iv = rsqrtf(var + BN_EPS);
        float sc = g[c] * iv;
        scale[c] = sc;
        shift[c] = be[c] - mu * sc;
    }
}

// ---------------------------------------------------------------------------
// Head with fused layer-3 BN apply.
__global__ __launch_bounds__(256) void k_logits(const float* __restrict__ abuf,
                                                const float* __restrict__ scale,
                                                const float* __restrict__ shift,
                                                const float* __restrict__ linW,
                                                const float* __restrict__ linb,
                                                float* __restrict__ logits,
                                                float* __restrict__ probs,
                                                float* __restrict__ x3out) {
    __shared__ float Xs[64][129];
    __shared__ float Ws[128 * 40];
    __shared__ float s_sc[128], s_sh[128];
    int tid = threadIdx.x;
    int m0 = blockIdx.x * 64;
    if (tid < 128) { s_sc[tid] = scale[tid]; s_sh[tid] = shift[tid]; }
    for (int q = tid; q < 1280; q += 256)
        *(float4*)&Ws[q * 4] = *(const float4*)&linW[q * 4];
    __syncthreads();
    for (int q = tid; q < 2048; q += 256) {
        int r = q >> 5, cf = (q & 31) << 2;
        float4 v = make_float4(0.f, 0.f, 0.f, 0.f);
        int m = m0 + r;
        if (m < N_NODES) {
            v = *(const float4*)&abuf[(size_t)m * 128 + cf];
            v.x = v.x * s_sc[cf + 0] + s_sh[cf + 0];
            v.y = v.y * s_sc[cf + 1] + s_sh[cf + 1];
            v.z = v.z * s_sc[cf + 2] + s_sh[cf + 2];
            v.w = v.w * s_sc[cf + 3] + s_sh[cf + 3];
            *(float4*)&x3out[(size_t)m * 128 + cf] = v;
        }
        *(float4*)&Xs[r][cf] = v;
    }
    __syncthreads();
    int r = tid >> 2;
    int cg = tid & 3;
    int cbase = cg * 10;
    float acc[10] = {};
    for (int k = 0; k < 128; k++) {
        float a = Xs[r][k];
#pragma unroll
        for (int j = 0; j < 10; j++) acc[j] += a * Ws[k * 40 + cbase + j];
    }
#pragma unroll
    for (int j = 0; j < 10; j++) acc[j] += linb[cbase + j];
    float m = acc[0];
#pragma unroll
    for (int j = 1; j < 10; j++) m = fmaxf(m, acc[j]);
    m = fmaxf(m, __shfl_xor(m, 1));
    m = fmaxf(m, __shfl_xor(m, 2));
    float ex[10];
    float s = 0.f;
#pragma unroll
    for (int j = 0; j < 10; j++) { ex[j] = expf(acc[j] - m); s += ex[j]; }
    s += __shfl_xor(s, 1);
    s += __shfl_xor(s, 2);
    float inv = 1.0f / s;
    int mrow = m0 + r;
    if (mrow < N_NODES) {
#pragma unroll
        for (int j = 0; j < 10; j++) {
            logits[(size_t)mrow * 40 + cbase + j] = acc[j];
            probs[(size_t)mrow * 40 + cbase + j] = ex[j] * inv;
        }
    }
}

// ---------------------------------------------------------------------------
extern "C" void kernel_launch(void* const* d_in, const int* in_sizes, int n_in,
                              void* d_out, int out_size, void* d_ws, size_t ws_size,
                              hipStream_t stream) {
    const float* x = (const float*)d_in[0];
    const unsigned int* eidx = (const unsigned int*)d_in[1];
    const float* ew = (const float*)d_in[2];
    const float* W1 = (const float*)d_in[3];
    const float* b1 = (const float*)d_in[4];
    const float* W2 = (const float*)d_in[5];
    const float* b2 = (const float*)d_in[6];
    const float* W3 = (const float*)d_in[7];
    const float* b3 = (const float*)d_in[8];
    const float* g1 = (const float*)d_in[9];
    const float* be1 = (const float*)d_in[10];
    const float* g2 = (const float*)d_in[11];
    const float* be2 = (const float*)d_in[12];
    const float* g3 = (const float*)d_in[13];
    const float* be3 = (const float*)d_in[14];
    const float* linW = (const float*)d_in[15];
    const float* linb = (const float*)d_in[16];

    float* out = (float*)d_out;
    float* logits = out;
    float* probs = out + (size_t)N_NODES * NCLASS;
    float* x3out = out + 2 * (size_t)N_NODES * NCLASS;

    char* ws = (char*)d_ws;
    size_t off = 0;
    auto take = [&](size_t bytes) -> char* {
        char* p = ws + off;
        off += (bytes + 255) & ~(size_t)255;
        return p;
    };
    int* row32 = (int*)take((size_t)N_EDGES * 4);
    int* col32 = (int*)take((size_t)N_EDGES * 4);
    int* slot = (int*)take((size_t)N_EDGES * 4);
    int* colptr = (int*)take((size_t)(N_NODES + 1) * 4);
    int* counts = (int*)take((size_t)N_NODES * 4);
    unsigned long long* degcnt = (unsigned long long*)take((size_t)N_NODES * 8);
    int* erow = (int*)take((size_t)N_EDGES * 4);
    float* enorm = (float*)take((size_t)N_EDGES * 4);
    float* dinv = (float*)take((size_t)N_NODES * 4);
    unsigned short* hbuf = (unsigned short*)take((size_t)N_NODES * NHID * 2);
    float* abuf = (float*)take((size_t)N_NODES * NHID * 4);
    unsigned short* W1t = (unsigned short*)take((size_t)512 * 128 * 2);
    unsigned short* W2t = (unsigned short*)take((size_t)128 * 128 * 2);
    unsigned short* W3t = (unsigned short*)take((size_t)128 * 128 * 2);
    float* psum = (float*)take((size_t)BN_BLOCKS * 128 * 4);
    float* psumsq = (float*)take((size_t)BN_BLOCKS * 128 * 4);
    float* scale = (float*)take(128 * 4);
    float* shift = (float*)take(128 * 4);
    int* bsum = (int*)take((size_t)SCAN_BLOCKS * 4);
    int* bpre = (int*)take((size_t)SCAN_BLOCKS * 4);
    int* flag = (int*)take(4);
    (void)ws_size; (void)n_in; (void)in_sizes; (void)out_size;

    const int TPB = 256;
    int grid_e = (N_EDGES + TPB - 1) / TPB;
    int grid_n = (N_NODES + TPB - 1) / TPB;
    int grid_gemm = (N_NODES + 127) / 128;        // 391
    int grid_agg = (N_NODES * 64 + TPB - 1) / TPB;
    int grid_head = (N_NODES + 63) / 64;          // 782

    // graph preprocessing
    k_detect<<<1, 256, 0, stream>>>(eidx, flag);
    k_convert<<<(2 * N_EDGES + TPB - 1) / TPB, TPB, 0, stream>>>(eidx, flag, row32, col32);
    k_init_node<<<grid_n, TPB, 0, stream>>>(degcnt);
    k_accum<<<grid_e, TPB, 0, stream>>>(col32, ew, degcnt, slot);
    k_dinv<<<grid_n, TPB, 0, stream>>>(degcnt, dinv, counts);
    k_scan1<<<SCAN_BLOCKS, TPB, 0, stream>>>(counts, bsum);
    k_scan2<<<1, TPB, 0, stream>>>(bsum, bpre, colptr);
    k_scan3<<<SCAN_BLOCKS, TPB, 0, stream>>>(counts, bpre, colptr);
    k_scatter<<<grid_e, TPB, 0, stream>>>(row32, col32, ew, dinv, colptr, slot, erow, enorm);
    k_prep_w<<<(98304 + TPB - 1) / TPB, TPB, 0, stream>>>(W1, W2, W3, W1t, W2t, W3t);

    // layer 1
    k_gemm_bf16<NFEAT, false><<<grid_gemm, TPB, 0, stream>>>(x, W1t, nullptr, nullptr, hbuf, N_NODES);
    k_aggregate<<<grid_agg, TPB, 0, stream>>>((const unsigned int*)hbuf, colptr, erow, enorm, dinv, b1, abuf, 1);
    k_bnstats<<<BN_BLOCKS, TPB, 0, stream>>>(abuf, psum, psumsq);
    k_bnfinal<<<1, 128, 0, stream>>>(psum, psumsq, g1, be1, scale, shift);

    // layer 2 (BN1 apply fused into GEMM A-staging)
    k_gemm_bf16<NHID, true><<<grid_gemm, TPB, 0, stream>>>(abuf, W2t, scale, shift, hbuf, N_NODES);
    k_aggregate<<<grid_agg, TPB, 0, stream>>>((const unsigned int*)hbuf, colptr, erow, enorm, dinv, b2, abuf, 1);
    k_bnstats<<<BN_BLOCKS, TPB, 0, stream>>>(abuf, psum, psumsq);
    k_bnfinal<<<1, 128, 0, stream>>>(psum, psumsq, g2, be2, scale, shift);

    // layer 3 (BN2 apply fused into GEMM; no relu on aggregate)
    k_gemm_bf16<NHID, true><<<grid_gemm, TPB, 0, stream>>>(abuf, W3t, scale, shift, hbuf, N_NODES);
    k_aggregate<<<grid_agg, TPB, 0, stream>>>((const unsigned int*)hbuf, colptr, erow, enorm, dinv, b3, abuf, 0);
    k_bnstats<<<BN_BLOCKS, TPB, 0, stream>>>(abuf, psum, psumsq);
    k_bnfinal<<<1, 128, 0, stream>>>(psum, psumsq, g3, be3, scale, shift);

    // head: BN3 apply + x3 write + logits + softmax, all fused
    k_logits<<<grid_head, TPB, 0, stream>>>(abuf, scale, shift, linW, linb, logits, probs, x3out);
}

// Round 7
// 526.002 us; speedup vs baseline: 1.9268x; 1.1012x over previous
//
#include <hip/hip_runtime.h>
#include <hip/hip_bf16.h>

#define N_NODES 50000
#define N_EDGES 800000
#define NFEAT 512
#define NHID 128
#define NCLASS 40
#define BN_EPS 1e-5f

typedef __attribute__((ext_vector_type(8))) short short8;
typedef __attribute__((ext_vector_type(4))) float f32x4;

__device__ __forceinline__ unsigned short f2b(float f) {
    unsigned int u = __float_as_uint(f);
    u += 0x7fff + ((u >> 16) & 1);   // RTNE
    return (unsigned short)(u >> 16);
}
__device__ __forceinline__ float blo(unsigned int v) {
    return __uint_as_float(v << 16);
}
__device__ __forceinline__ float bhi(unsigned int v) {
    return __uint_as_float(v & 0xffff0000u);
}

// ---------------------------------------------------------------------------
// Edge-index dtype detection (int64 ref layout vs int32 handed by harness).
__global__ void k_detect(const unsigned int* __restrict__ words, int* __restrict__ flag) {
    __shared__ int s_any;
    if (threadIdx.x == 0) s_any = 0;
    __syncthreads();
    unsigned int v = words[2 * threadIdx.x + 1];
    if (v != 0) atomicAdd(&s_any, 1);
    __syncthreads();
    if (threadIdx.x == 0) *flag = (s_any == 0) ? 1 : 0;  // 1 => int64 layout
}

__global__ void k_init_node(unsigned long long* __restrict__ degcnt) {
    int i = blockIdx.x * blockDim.x + threadIdx.x;
    if (i < N_NODES) degcnt[i] = 0ULL;
}

// Fused convert + accum: decode edge index once, one 64-bit atomic per edge.
// High word = count (returned old = CSR slot), low = fixed-point ew sum.
__global__ void k_convert_accum(const unsigned int* __restrict__ words,
                                const int* __restrict__ flag,
                                const float* __restrict__ ew,
                                int* __restrict__ row, int* __restrict__ col,
                                unsigned long long* __restrict__ degcnt,
                                int* __restrict__ slot) {
    int e = blockIdx.x * blockDim.x + threadIdx.x;
    if (e >= N_EDGES) return;
    int f = *flag;
    unsigned int r = f ? words[2 * (size_t)e] : words[e];
    unsigned int c = f ? words[2 * ((size_t)e + N_EDGES)] : words[e + N_EDGES];
    row[e] = (int)r;
    col[e] = (int)c;
    unsigned int q = __float2uint_rn(ew[e] * 8388608.0f);  // 2^23
    unsigned long long old = atomicAdd(&degcnt[c], (1ULL << 32) | (unsigned long long)q);
    slot[e] = (int)(old >> 32);
}

// ---------------------------------------------------------------------------
#define SCAN_BLOCKS ((N_NODES + 255) / 256)   // 196

// dinv + counts extraction + scan phase-1 block reduction, fused.
__global__ __launch_bounds__(256) void k_dinv(const unsigned long long* __restrict__ degcnt,
                                              float* __restrict__ dinv,
                                              int* __restrict__ counts,
                                              int* __restrict__ bsum) {
    int i = blockIdx.x * 256 + threadIdx.x;
    int cnt = 0;
    if (i < N_NODES) {
        unsigned long long v = degcnt[i];
        float deg = 1.0f + (float)(unsigned int)(v & 0xffffffffULL) * (1.0f / 8388608.0f);
        dinv[i] = rsqrtf(deg);
        cnt = (int)(v >> 32);
        counts[i] = cnt;
    }
    __shared__ int sh[256];
    sh[threadIdx.x] = cnt;
    __syncthreads();
    for (int ofs = 128; ofs > 0; ofs >>= 1) {
        if (threadIdx.x < ofs) sh[threadIdx.x] += sh[threadIdx.x + ofs];
        __syncthreads();
    }
    if (threadIdx.x == 0) bsum[blockIdx.x] = sh[0];
}

__global__ __launch_bounds__(256) void k_scan2(const int* __restrict__ bsum,
                                               int* __restrict__ bpre,
                                               int* __restrict__ colptr) {
    int t = threadIdx.x;
    int v = (t < SCAN_BLOCKS) ? bsum[t] : 0;
    __shared__ int sh[256];
    sh[t] = v;
    __syncthreads();
    for (int ofs = 1; ofs < 256; ofs <<= 1) {
        int u = (t >= ofs) ? sh[t - ofs] : 0;
        __syncthreads();
        sh[t] += u;
        __syncthreads();
    }
    if (t < SCAN_BLOCKS) bpre[t] = sh[t] - v;  // exclusive
    if (t == SCAN_BLOCKS - 1) colptr[N_NODES] = sh[t];
}

__global__ __launch_bounds__(256) void k_scan3(const int* __restrict__ counts,
                                               const int* __restrict__ bpre,
                                               int* __restrict__ colptr) {
    int t = threadIdx.x;
    int i = blockIdx.x * 256 + t;
    int v = (i < N_NODES) ? counts[i] : 0;
    __shared__ int sh[256];
    sh[t] = v;
    __syncthreads();
    for (int ofs = 1; ofs < 256; ofs <<= 1) {
        int u = (t >= ofs) ? sh[t - ofs] : 0;
        __syncthreads();
        sh[t] += u;
        __syncthreads();
    }
    if (i < N_NODES) colptr[i] = bpre[blockIdx.x] + sh[t] - v;
}

// Atomic-free scatter into interleaved (row, norm) records.
__global__ void k_scatter(const int* __restrict__ row, const int* __restrict__ col,
                          const float* __restrict__ ew, const float* __restrict__ dinv,
                          const int* __restrict__ colptr, const int* __restrict__ slot,
                          int2* __restrict__ ern) {
    int e = blockIdx.x * blockDim.x + threadIdx.x;
    if (e < N_EDGES) {
        int c = col[e], r = row[e];
        int p = colptr[c] + slot[e];
        float nrm = dinv[r] * ew[e] * dinv[c];
        ern[p] = make_int2(r, __float_as_int(nrm));
    }
}

// ---------------------------------------------------------------------------
// Weight prep: fp32 W[K][128] -> bf16 W^T[128][K], for W1,W2,W3.
__global__ void k_prep_w(const float* __restrict__ W1, const float* __restrict__ W2,
                         const float* __restrict__ W3, unsigned short* __restrict__ W1t,
                         unsigned short* __restrict__ W2t, unsigned short* __restrict__ W3t) {
    int i = blockIdx.x * blockDim.x + threadIdx.x;
    if (i < 65536) {
        int k = i >> 7, n = i & 127;
        W1t[n * 512 + k] = f2b(W1[i]);
    } else if (i < 81920) {
        int j = i - 65536; int k = j >> 7, n = j & 127;
        W2t[n * 128 + k] = f2b(W2[j]);
    } else if (i < 98304) {
        int j = i - 81920; int k = j >> 7, n = j & 127;
        W3t[n * 128 + k] = f2b(W3[j]);
    }
}

// ---------------------------------------------------------------------------
// bf16 MFMA GEMM: Out[M,128](bf16) = A[M,K] @ W[K,128]. BM=128 BN=128 BK=32.
// A is fp32 (layer 1) or packed bf16 (layers 2/3, with BN scale/shift fused).
template <int K, bool FUSE, bool ABF16>
__global__ __launch_bounds__(256) void k_gemm_bf16(
    const void* __restrict__ Av, const unsigned short* __restrict__ Wt,
    const float* __restrict__ scale, const float* __restrict__ shift,
    unsigned short* __restrict__ Out, int M) {
    __shared__ unsigned short As[128][40];
    __shared__ unsigned short Bs[128][40];
    __shared__ float s_sc[128], s_sh[128];
    int tid = threadIdx.x;
    int m0 = blockIdx.x * 128;
    if (FUSE) {
        if (tid < 128) { s_sc[tid] = scale[tid]; s_sh[tid] = shift[tid]; }
        __syncthreads();
    }
    int srow = tid >> 1;        // 0..127
    int skh = (tid & 1) << 4;   // 0 or 16 (shorts within the 32-wide k-tile)
    int wave = tid >> 6, lane = tid & 63;
    int wm = (wave >> 1) * 64, wn = (wave & 1) * 64;
    int l15 = lane & 15, quad = lane >> 4;
    f32x4 acc[4][4] = {};
    bool arow_ok = (m0 + srow) < M;
    const float* arow_f = (const float*)Av + (size_t)(m0 + srow) * K + skh;
    const unsigned int* arow_b = (const unsigned int*)Av + (size_t)(m0 + srow) * (K / 2) + (skh >> 1);
    const unsigned short* wrow_p = Wt + (size_t)srow * K + skh;
    for (int kt = 0; kt < K; kt += 32) {
        unsigned int p[8];
        if (ABF16) {
            uint4 r0 = make_uint4(0, 0, 0, 0), r1 = make_uint4(0, 0, 0, 0);
            if (arow_ok) {
                r0 = *(const uint4*)(arow_b + (kt >> 1));
                r1 = *(const uint4*)(arow_b + (kt >> 1) + 4);
            }
            unsigned int raw[8] = {r0.x, r0.y, r0.z, r0.w, r1.x, r1.y, r1.z, r1.w};
#pragma unroll
            for (int q = 0; q < 8; q++) {
                if (FUSE) {
                    int ch = kt + skh + 2 * q;
                    float f0 = blo(raw[q]) * s_sc[ch] + s_sh[ch];
                    float f1 = bhi(raw[q]) * s_sc[ch + 1] + s_sh[ch + 1];
                    p[q] = (unsigned int)f2b(f0) | ((unsigned int)f2b(f1) << 16);
                } else {
                    p[q] = raw[q];
                }
            }
        } else {
            float v[16];
#pragma unroll
            for (int q = 0; q < 4; q++) {
                float4 t4 = make_float4(0.f, 0.f, 0.f, 0.f);
                if (arow_ok) t4 = *(const float4*)(arow_f + kt + q * 4);
                v[q * 4 + 0] = t4.x; v[q * 4 + 1] = t4.y;
                v[q * 4 + 2] = t4.z; v[q * 4 + 3] = t4.w;
            }
            if (FUSE) {
#pragma unroll
                for (int q = 0; q < 16; q++)
                    v[q] = v[q] * s_sc[kt + skh + q] + s_sh[kt + skh + q];
            }
#pragma unroll
            for (int q = 0; q < 8; q++)
                p[q] = (unsigned int)f2b(v[2 * q]) | ((unsigned int)f2b(v[2 * q + 1]) << 16);
        }
        uint4 w0 = make_uint4(p[0], p[1], p[2], p[3]);
        uint4 w1 = make_uint4(p[4], p[5], p[6], p[7]);
        uint4 b0 = *(const uint4*)(wrow_p + kt);
        uint4 b1 = *(const uint4*)(wrow_p + kt + 8);
        *(uint4*)&As[srow][skh] = w0;
        *(uint4*)&As[srow][skh + 8] = w1;
        *(uint4*)&Bs[srow][skh] = b0;
        *(uint4*)&Bs[srow][skh + 8] = b1;
        __syncthreads();
        short8 a[4], b[4];
#pragma unroll
        for (int i = 0; i < 4; i++) a[i] = *(const short8*)&As[wm + i * 16 + l15][quad * 8];
#pragma unroll
        for (int j = 0; j < 4; j++) b[j] = *(const short8*)&Bs[wn + j * 16 + l15][quad * 8];
#pragma unroll
        for (int i = 0; i < 4; i++)
#pragma unroll
            for (int j = 0; j < 4; j++)
                acc[i][j] = __builtin_amdgcn_mfma_f32_16x16x32_bf16(a[i], b[j], acc[i][j], 0, 0, 0);
        __syncthreads();
    }
#pragma unroll
    for (int i = 0; i < 4; i++) {
        int mb = m0 + wm + i * 16 + quad * 4;
#pragma unroll
        for (int r = 0; r < 4; r++) {
            int m = mb + r;
            if (m < M) {
#pragma unroll
                for (int j = 0; j < 4; j++)
                    Out[(size_t)m * 128 + wn + j * 16 + l15] = f2b(acc[i][j][r]);
            }
        }
    }
}

// ---------------------------------------------------------------------------
// CSR aggregation: one wave per node, h bf16 (uint per lane = channels 2l,2l+1),
// fp32 accumulate, 8-way unrolled with dual accumulator pairs. bf16 packed out.
__global__ __launch_bounds__(256) void k_aggregate(
    const unsigned int* __restrict__ hb, const int* __restrict__ colptr,
    const int2* __restrict__ ern, const float* __restrict__ dinv,
    const float* __restrict__ bias, unsigned int* __restrict__ out, int relu) {
    int node = (blockIdx.x * blockDim.x + threadIdx.x) >> 6;
    int lane = threadIdx.x & 63;
    if (node >= N_NODES) return;
    float di = dinv[node];
    float selfw = di * di;
    unsigned int sv = hb[(size_t)node * 64 + lane];
    float a0 = selfw * blo(sv);
    float a1 = selfw * bhi(sv);
    float c0 = 0.f, c1 = 0.f;
    int e = colptr[node], end = colptr[node + 1];
    for (; e + 8 <= end; e += 8) {
        int2 rw[8];
#pragma unroll
        for (int q = 0; q < 8; q++) rw[q] = ern[e + q];
        unsigned int v[8];
#pragma unroll
        for (int q = 0; q < 8; q++) v[q] = hb[(size_t)rw[q].x * 64 + lane];
#pragma unroll
        for (int q = 0; q < 8; q++) {
            float w = __int_as_float(rw[q].y);
            if (q & 1) { c0 += w * blo(v[q]); c1 += w * bhi(v[q]); }
            else       { a0 += w * blo(v[q]); a1 += w * bhi(v[q]); }
        }
    }
    for (; e < end; e++) {
        int2 rw = ern[e];
        float w = __int_as_float(rw.y);
        unsigned int v = hb[(size_t)rw.x * 64 + lane];
        a0 += w * blo(v);
        a1 += w * bhi(v);
    }
    a0 += c0; a1 += c1;
    float2 bv = *(const float2*)&bias[2 * lane];
    a0 += bv.x;
    a1 += bv.y;
    if (relu) { a0 = fmaxf(a0, 0.f); a1 = fmaxf(a1, 0.f); }
    out[(size_t)node * 64 + lane] = (unsigned int)f2b(a0) | ((unsigned int)f2b(a1) << 16);
}

// ---------------------------------------------------------------------------
// BatchNorm stats over bf16-packed abuf: per-block partials, then reduce.
#define BN_BLOCKS ((N_NODES + 255) / 256)

__global__ __launch_bounds__(256) void k_bnstats(const unsigned int* __restrict__ x,
                                                 float* __restrict__ psum,
                                                 float* __restrict__ psumsq) {
    int u = threadIdx.x & 63;      // uint column (channels 2u, 2u+1)
    int strip = threadIdx.x >> 6;  // 0..3
    int r0 = blockIdx.x * 256;
    int rend = min(r0 + 256, N_NODES);
    float sl = 0.f, s2l = 0.f, sh_ = 0.f, s2h = 0.f;
    for (int r = r0 + strip; r < rend; r += 4) {
        unsigned int v = x[(size_t)r * 64 + u];
        float a = blo(v), b = bhi(v);
        sl += a; s2l += a * a;
        sh_ += b; s2h += b * b;
    }
    __shared__ float buf[4][64][4];
    buf[strip][u][0] = sl; buf[strip][u][1] = s2l;
    buf[strip][u][2] = sh_; buf[strip][u][3] = s2h;
    __syncthreads();
    if (strip == 0) {
#pragma unroll
        for (int s = 1; s < 4; s++) {
            sl += buf[s][u][0]; s2l += buf[s][u][1];
            sh_ += buf[s][u][2]; s2h += buf[s][u][3];
        }
        psum[blockIdx.x * 128 + 2 * u] = sl;
        psum[blockIdx.x * 128 + 2 * u + 1] = sh_;
        psumsq[blockIdx.x * 128 + 2 * u] = s2l;
        psumsq[blockIdx.x * 128 + 2 * u + 1] = s2h;
    }
}

__global__ void k_bnfinal(const float* __restrict__ psum, const float* __restrict__ psumsq,
                          const float* __restrict__ g, const float* __restrict__ be,
                          float* __restrict__ scale, float* __restrict__ shift) {
    int c = threadIdx.x;
    if (c < 128) {
        float s = 0.f, s2 = 0.f;
        for (int b = 0; b < BN_BLOCKS; b++) {
            s += psum[b * 128 + c];
            s2 += psumsq[b * 128 + c];
        }
        const float invn = 1.0f / (float)N_NODES;
        float mu = s * invn;
        float var = s2 * invn - mu * mu;
        float iv = rsqrtf(var + BN_EPS);
        float sc = g[c] * iv;
        scale[c] = sc;
        shift[c] = be[c] - mu * sc;
    }
}

// ---------------------------------------------------------------------------
// Head: fused BN3 apply (abuf bf16 -> x3 fp32 in d_out) + logits + softmax.
__global__ __launch_bounds__(256) void k_logits(const unsigned int* __restrict__ abuf,
                                                const float* __restrict__ scale,
                                                const float* __restrict__ shift,
                                                const float* __restrict__ linW,
                                                const float* __restrict__ linb,
                                                float* __restrict__ logits,
                                                float* __restrict__ probs,
                                                float* __restrict__ x3out) {
    __shared__ float Xs[64][130];
    __shared__ float Ws[128 * 40];
    __shared__ float s_sc[128], s_sh[128];
    int tid = threadIdx.x;
    int m0 = blockIdx.x * 64;
    if (tid < 128) { s_sc[tid] = scale[tid]; s_sh[tid] = shift[tid]; }
    for (int q = tid; q < 1280; q += 256)
        *(float4*)&Ws[q * 4] = *(const float4*)&linW[q * 4];
    __syncthreads();
    for (int q = tid; q < 4096; q += 256) {
        int r = q >> 6, u = q & 63;
        int m = m0 + r;
        float f0 = 0.f, f1 = 0.f;
        if (m < N_NODES) {
            unsigned int v = abuf[(size_t)m * 64 + u];
            f0 = blo(v) * s_sc[2 * u] + s_sh[2 * u];
            f1 = bhi(v) * s_sc[2 * u + 1] + s_sh[2 * u + 1];
            *(float2*)&x3out[(size_t)m * 128 + 2 * u] = make_float2(f0, f1);
        }
        *(float2*)&Xs[r][2 * u] = make_float2(f0, f1);
    }
    __syncthreads();
    int r = tid >> 2;
    int cg = tid & 3;
    int cbase = cg * 10;
    float acc[10] = {};
    for (int k = 0; k < 128; k++) {
        float a = Xs[r][k];
#pragma unroll
        for (int j = 0; j < 10; j++) acc[j] += a * Ws[k * 40 + cbase + j];
    }
#pragma unroll
    for (int j = 0; j < 10; j++) acc[j] += linb[cbase + j];
    float m = acc[0];
#pragma unroll
    for (int j = 1; j < 10; j++) m = fmaxf(m, acc[j]);
    m = fmaxf(m, __shfl_xor(m, 1));
    m = fmaxf(m, __shfl_xor(m, 2));
    float ex[10];
    float s = 0.f;
#pragma unroll
    for (int j = 0; j < 10; j++) { ex[j] = expf(acc[j] - m); s += ex[j]; }
    s += __shfl_xor(s, 1);
    s += __shfl_xor(s, 2);
    float inv = 1.0f / s;
    int mrow = m0 + r;
    if (mrow < N_NODES) {
#pragma unroll
        for (int j = 0; j < 10; j++) {
            logits[(size_t)mrow * 40 + cbase + j] = acc[j];
            probs[(size_t)mrow * 40 + cbase + j] = ex[j] * inv;
        }
    }
}

// ---------------------------------------------------------------------------
extern "C" void kernel_launch(void* const* d_in, const int* in_sizes, int n_in,
                              void* d_out, int out_size, void* d_ws, size_t ws_size,
                              hipStream_t stream) {
    const float* x = (const float*)d_in[0];
    const unsigned int* eidx = (const unsigned int*)d_in[1];
    const float* ew = (const float*)d_in[2];
    const float* W1 = (const float*)d_in[3];
    const float* b1 = (const float*)d_in[4];
    const float* W2 = (const float*)d_in[5];
    const float* b2 = (const float*)d_in[6];
    const float* W3 = (const float*)d_in[7];
    const float* b3 = (const float*)d_in[8];
    const float* g1 = (const float*)d_in[9];
    const float* be1 = (const float*)d_in[10];
    const float* g2 = (const float*)d_in[11];
    const float* be2 = (const float*)d_in[12];
    const float* g3 = (const float*)d_in[13];
    const float* be3 = (const float*)d_in[14];
    const float* linW = (const float*)d_in[15];
    const float* linb = (const float*)d_in[16];

    float* out = (float*)d_out;
    float* logits = out;
    float* probs = out + (size_t)N_NODES * NCLASS;
    float* x3out = out + 2 * (size_t)N_NODES * NCLASS;

    char* ws = (char*)d_ws;
    size_t off = 0;
    auto take = [&](size_t bytes) -> char* {
        char* p = ws + off;
        off += (bytes + 255) & ~(size_t)255;
        return p;
    };
    int* row32 = (int*)take((size_t)N_EDGES * 4);
    int* col32 = (int*)take((size_t)N_EDGES * 4);
    int* slot = (int*)take((size_t)N_EDGES * 4);
    int* colptr = (int*)take((size_t)(N_NODES + 1) * 4);
    int* counts = (int*)take((size_t)N_NODES * 4);
    unsigned long long* degcnt = (unsigned long long*)take((size_t)N_NODES * 8);
    int2* ern = (int2*)take((size_t)N_EDGES * 8);
    float* dinv = (float*)take((size_t)N_NODES * 4);
    unsigned short* hbuf = (unsigned short*)take((size_t)N_NODES * NHID * 2);
    unsigned short* abuf = (unsigned short*)take((size_t)N_NODES * NHID * 2);
    unsigned short* W1t = (unsigned short*)take((size_t)512 * 128 * 2);
    unsigned short* W2t = (unsigned short*)take((size_t)128 * 128 * 2);
    unsigned short* W3t = (unsigned short*)take((size_t)128 * 128 * 2);
    float* psum = (float*)take((size_t)BN_BLOCKS * 128 * 4);
    float* psumsq = (float*)take((size_t)BN_BLOCKS * 128 * 4);
    float* scale = (float*)take(128 * 4);
    float* shift = (float*)take(128 * 4);
    int* bsum = (int*)take((size_t)SCAN_BLOCKS * 4);
    int* bpre = (int*)take((size_t)SCAN_BLOCKS * 4);
    int* flag = (int*)take(4);
    (void)ws_size; (void)n_in; (void)in_sizes; (void)out_size;

    const int TPB = 256;
    int grid_e = (N_EDGES + TPB - 1) / TPB;
    int grid_gemm = (N_NODES + 127) / 128;        // 391
    int grid_agg = (N_NODES * 64 + TPB - 1) / TPB;
    int grid_head = (N_NODES + 63) / 64;          // 782

    // graph preprocessing
    k_detect<<<1, 256, 0, stream>>>(eidx, flag);
    k_init_node<<<SCAN_BLOCKS, TPB, 0, stream>>>(degcnt);
    k_convert_accum<<<grid_e, TPB, 0, stream>>>(eidx, flag, ew, row32, col32, degcnt, slot);
    k_dinv<<<SCAN_BLOCKS, TPB, 0, stream>>>(degcnt, dinv, counts, bsum);
    k_scan2<<<1, TPB, 0, stream>>>(bsum, bpre, colptr);
    k_scan3<<<SCAN_BLOCKS, TPB, 0, stream>>>(counts, bpre, colptr);
    k_scatter<<<grid_e, TPB, 0, stream>>>(row32, col32, ew, dinv, colptr, slot, ern);
    k_prep_w<<<(98304 + TPB - 1) / TPB, TPB, 0, stream>>>(W1, W2, W3, W1t, W2t, W3t);

    // layer 1
    k_gemm_bf16<NFEAT, false, false><<<grid_gemm, TPB, 0, stream>>>(x, W1t, nullptr, nullptr, hbuf, N_NODES);
    k_aggregate<<<grid_agg, TPB, 0, stream>>>((const unsigned int*)hbuf, colptr, ern, dinv, b1, (unsigned int*)abuf, 1);
    k_bnstats<<<BN_BLOCKS, TPB, 0, stream>>>((const unsigned int*)abuf, psum, psumsq);
    k_bnfinal<<<1, 128, 0, stream>>>(psum, psumsq, g1, be1, scale, shift);

    // layer 2 (BN1 apply fused into GEMM A-staging, A bf16)
    k_gemm_bf16<NHID, true, true><<<grid_gemm, TPB, 0, stream>>>(abuf, W2t, scale, shift, hbuf, N_NODES);
    k_aggregate<<<grid_agg, TPB, 0, stream>>>((const unsigned int*)hbuf, colptr, ern, dinv, b2, (unsigned int*)abuf, 1);
    k_bnstats<<<BN_BLOCKS, TPB, 0, stream>>>((const unsigned int*)abuf, psum, psumsq);
    k_bnfinal<<<1, 128, 0, stream>>>(psum, psumsq, g2, be2, scale, shift);

    // layer 3 (BN2 apply fused into GEMM; no relu on aggregate)
    k_gemm_bf16<NHID, true, true><<<grid_gemm, TPB, 0, stream>>>(abuf, W3t, scale, shift, hbuf, N_NODES);
    k_aggregate<<<grid_agg, TPB, 0, stream>>>((const unsigned int*)hbuf, colptr, ern, dinv, b3, (unsigned int*)abuf, 0);
    k_bnstats<<<BN_BLOCKS, TPB, 0, stream>>>((const unsigned int*)abuf, psum, psumsq);
    k_bnfinal<<<1, 128, 0, stream>>>(psum, psumsq, g3, be3, scale, shift);

    // head: BN3 apply + x3 write + logits + softmax, all fused
    k_logits<<<grid_head, TPB, 0, stream>>>((const unsigned int*)abuf, scale, shift, linW, linb, logits, probs, x3out);
}

// Round 8
// 494.611 us; speedup vs baseline: 2.0491x; 1.0635x over previous
//
#include <hip/hip_runtime.h>
#include <hip/hip_bf16.h>

#define N_NODES 50000
#define N_EDGES 800000
#define NFEAT 512
#define NHID 128
#define NCLASS 40
#define BN_EPS 1e-5f

typedef __attribute__((ext_vector_type(8))) short short8;
typedef __attribute__((ext_vector_type(4))) float f32x4;

#define GEMM1_BLOCKS ((N_NODES + 127) / 128)   // 391
#define EDGE_BLOCKS ((N_EDGES + 255) / 256)    // 3125
#define SCAN_BLOCKS ((N_NODES + 255) / 256)    // 196
#define BN_BLOCKS ((N_NODES + 255) / 256)      // 196

__device__ __forceinline__ unsigned short f2b(float f) {
    unsigned int u = __float_as_uint(f);
    u += 0x7fff + ((u >> 16) & 1);   // RTNE
    return (unsigned short)(u >> 16);
}
__device__ __forceinline__ float blo(unsigned int v) {
    return __uint_as_float(v << 16);
}
__device__ __forceinline__ float bhi(unsigned int v) {
    return __uint_as_float(v & 0xffff0000u);
}

// ---------------------------------------------------------------------------
__global__ void k_init_node(unsigned long long* __restrict__ degcnt) {
    int i = blockIdx.x * blockDim.x + threadIdx.x;
    if (i < N_NODES) degcnt[i] = 0ULL;
}

// Weight prep: fp32 W[K][128] -> bf16 W^T[128][K], for W1,W2,W3.
__global__ void k_prep_w(const float* __restrict__ W1, const float* __restrict__ W2,
                         const float* __restrict__ W3, unsigned short* __restrict__ W1t,
                         unsigned short* __restrict__ W2t, unsigned short* __restrict__ W3t) {
    int i = blockIdx.x * blockDim.x + threadIdx.x;
    if (i < 65536) {
        int k = i >> 7, n = i & 127;
        W1t[n * 512 + k] = f2b(W1[i]);
    } else if (i < 81920) {
        int j = i - 65536; int k = j >> 7, n = j & 127;
        W2t[n * 128 + k] = f2b(W2[j]);
    } else if (i < 98304) {
        int j = i - 81920; int k = j >> 7, n = j & 127;
        W3t[n * 128 + k] = f2b(W3[j]);
    }
}

// ---------------------------------------------------------------------------
// FAT kernel: blocks [0,391) run layer-1 GEMM (x fp32 @ W1 -> hbuf bf16);
// blocks [391, 391+3125) run edge convert+histogram (independent work, one
// launch so the atomic latency hides under MFMA compute).
__global__ __launch_bounds__(256) void k_fat(
    const float* __restrict__ x, const unsigned short* __restrict__ W1t,
    unsigned short* __restrict__ hbuf,
    const unsigned int* __restrict__ words, const float* __restrict__ ew,
    int* __restrict__ row, int* __restrict__ col,
    unsigned long long* __restrict__ degcnt, int* __restrict__ slot) {
    __shared__ unsigned short As[128][40];
    __shared__ unsigned short Bs[128][40];
    __shared__ int s_any;
    int tid = threadIdx.x;
    if (blockIdx.x < GEMM1_BLOCKS) {
        // ---- layer-1 GEMM: BM=128 BN=128 BK=32, K=512 ----
        int m0 = blockIdx.x * 128;
        int srow = tid >> 1;
        int skh = (tid & 1) << 4;
        int wave = tid >> 6, lane = tid & 63;
        int wm = (wave >> 1) * 64, wn = (wave & 1) * 64;
        int l15 = lane & 15, quad = lane >> 4;
        f32x4 acc[4][4] = {};
        bool arow_ok = (m0 + srow) < N_NODES;
        const float* arow_p = x + (size_t)(m0 + srow) * 512 + skh;
        const unsigned short* wrow_p = W1t + (size_t)srow * 512 + skh;
        for (int kt = 0; kt < 512; kt += 32) {
            float v[16];
#pragma unroll
            for (int q = 0; q < 4; q++) {
                float4 t4 = make_float4(0.f, 0.f, 0.f, 0.f);
                if (arow_ok) t4 = *(const float4*)(arow_p + kt + q * 4);
                v[q * 4 + 0] = t4.x; v[q * 4 + 1] = t4.y;
                v[q * 4 + 2] = t4.z; v[q * 4 + 3] = t4.w;
            }
            unsigned int p[8];
#pragma unroll
            for (int q = 0; q < 8; q++)
                p[q] = (unsigned int)f2b(v[2 * q]) | ((unsigned int)f2b(v[2 * q + 1]) << 16);
            uint4 w0 = make_uint4(p[0], p[1], p[2], p[3]);
            uint4 w1 = make_uint4(p[4], p[5], p[6], p[7]);
            uint4 b0 = *(const uint4*)(wrow_p + kt);
            uint4 b1 = *(const uint4*)(wrow_p + kt + 8);
            *(uint4*)&As[srow][skh] = w0;
            *(uint4*)&As[srow][skh + 8] = w1;
            *(uint4*)&Bs[srow][skh] = b0;
            *(uint4*)&Bs[srow][skh + 8] = b1;
            __syncthreads();
            short8 a[4], b[4];
#pragma unroll
            for (int i = 0; i < 4; i++) a[i] = *(const short8*)&As[wm + i * 16 + l15][quad * 8];
#pragma unroll
            for (int j = 0; j < 4; j++) b[j] = *(const short8*)&Bs[wn + j * 16 + l15][quad * 8];
#pragma unroll
            for (int i = 0; i < 4; i++)
#pragma unroll
                for (int j = 0; j < 4; j++)
                    acc[i][j] = __builtin_amdgcn_mfma_f32_16x16x32_bf16(a[i], b[j], acc[i][j], 0, 0, 0);
            __syncthreads();
        }
#pragma unroll
        for (int i = 0; i < 4; i++) {
            int mb = m0 + wm + i * 16 + quad * 4;
#pragma unroll
            for (int r = 0; r < 4; r++) {
                int m = mb + r;
                if (m < N_NODES) {
#pragma unroll
                    for (int j = 0; j < 4; j++)
                        hbuf[(size_t)m * 128 + wn + j * 16 + l15] = f2b(acc[i][j][r]);
                }
            }
        }
    } else {
        // ---- edge convert + degree histogram (per-block inline detect) ----
        if (tid == 0) s_any = 0;
        __syncthreads();
        unsigned int probe = words[2 * tid + 1];
        if (probe != 0) atomicAdd(&s_any, 1);
        __syncthreads();
        int f = (s_any == 0) ? 1 : 0;  // 1 => int64 layout
        int e = (blockIdx.x - GEMM1_BLOCKS) * 256 + tid;
        if (e < N_EDGES) {
            unsigned int r = f ? words[2 * (size_t)e] : words[e];
            unsigned int c = f ? words[2 * ((size_t)e + N_EDGES)] : words[e + N_EDGES];
            row[e] = (int)r;
            col[e] = (int)c;
            unsigned int q = __float2uint_rn(ew[e] * 8388608.0f);  // 2^23 fixed point
            unsigned long long old = atomicAdd(&degcnt[c], (1ULL << 32) | (unsigned long long)q);
            slot[e] = (int)(old >> 32);
        }
    }
}

// ---------------------------------------------------------------------------
// dinv + counts extraction + scan phase-1 block reduction, fused.
__global__ __launch_bounds__(256) void k_dinv(const unsigned long long* __restrict__ degcnt,
                                              float* __restrict__ dinv,
                                              int* __restrict__ counts,
                                              int* __restrict__ bsum) {
    int i = blockIdx.x * 256 + threadIdx.x;
    int cnt = 0;
    if (i < N_NODES) {
        unsigned long long v = degcnt[i];
        float deg = 1.0f + (float)(unsigned int)(v & 0xffffffffULL) * (1.0f / 8388608.0f);
        dinv[i] = rsqrtf(deg);
        cnt = (int)(v >> 32);
        counts[i] = cnt;
    }
    __shared__ int sh[256];
    sh[threadIdx.x] = cnt;
    __syncthreads();
    for (int ofs = 128; ofs > 0; ofs >>= 1) {
        if (threadIdx.x < ofs) sh[threadIdx.x] += sh[threadIdx.x + ofs];
        __syncthreads();
    }
    if (threadIdx.x == 0) bsum[blockIdx.x] = sh[0];
}

__global__ __launch_bounds__(256) void k_scan2(const int* __restrict__ bsum,
                                               int* __restrict__ bpre,
                                               int* __restrict__ colptr) {
    int t = threadIdx.x;
    int v = (t < SCAN_BLOCKS) ? bsum[t] : 0;
    __shared__ int sh[256];
    sh[t] = v;
    __syncthreads();
    for (int ofs = 1; ofs < 256; ofs <<= 1) {
        int u = (t >= ofs) ? sh[t - ofs] : 0;
        __syncthreads();
        sh[t] += u;
        __syncthreads();
    }
    if (t < SCAN_BLOCKS) bpre[t] = sh[t] - v;  // exclusive
    if (t == SCAN_BLOCKS - 1) colptr[N_NODES] = sh[t];
}

__global__ __launch_bounds__(256) void k_scan3(const int* __restrict__ counts,
                                               const int* __restrict__ bpre,
                                               int* __restrict__ colptr) {
    int t = threadIdx.x;
    int i = blockIdx.x * 256 + t;
    int v = (i < N_NODES) ? counts[i] : 0;
    __shared__ int sh[256];
    sh[t] = v;
    __syncthreads();
    for (int ofs = 1; ofs < 256; ofs <<= 1) {
        int u = (t >= ofs) ? sh[t - ofs] : 0;
        __syncthreads();
        sh[t] += u;
        __syncthreads();
    }
    if (i < N_NODES) colptr[i] = bpre[blockIdx.x] + sh[t] - v;
}

// Atomic-free scatter into interleaved (row, norm) records.
__global__ void k_scatter(const int* __restrict__ row, const int* __restrict__ col,
                          const float* __restrict__ ew, const float* __restrict__ dinv,
                          const int* __restrict__ colptr, const int* __restrict__ slot,
                          int2* __restrict__ ern) {
    int e = blockIdx.x * blockDim.x + threadIdx.x;
    if (e < N_EDGES) {
        int c = col[e], r = row[e];
        int p = colptr[c] + slot[e];
        float nrm = dinv[r] * ew[e] * dinv[c];
        ern[p] = make_int2(r, __float_as_int(nrm));
    }
}

// ---------------------------------------------------------------------------
// CSR aggregation: one wave per node, h bf16, fp32 accumulate, 8-way unrolled.
// Block 0 also zeroes sums/sumsq for the following bnstats (runs pre-bnstats,
// post previous consumer — stream order makes this safe).
__global__ __launch_bounds__(256) void k_aggregate(
    const unsigned int* __restrict__ hb, const int* __restrict__ colptr,
    const int2* __restrict__ ern, const float* __restrict__ dinv,
    const float* __restrict__ bias, unsigned int* __restrict__ out, int relu,
    float* __restrict__ sums, float* __restrict__ sumsq) {
    if (blockIdx.x == 0) {
        if (threadIdx.x < 128) sums[threadIdx.x] = 0.f;
        else sumsq[threadIdx.x - 128] = 0.f;
    }
    int node = (blockIdx.x * blockDim.x + threadIdx.x) >> 6;
    int lane = threadIdx.x & 63;
    if (node >= N_NODES) return;
    float di = dinv[node];
    float selfw = di * di;
    unsigned int sv = hb[(size_t)node * 64 + lane];
    float a0 = selfw * blo(sv);
    float a1 = selfw * bhi(sv);
    float c0 = 0.f, c1 = 0.f;
    int e = colptr[node], end = colptr[node + 1];
    for (; e + 8 <= end; e += 8) {
        int2 rw[8];
#pragma unroll
        for (int q = 0; q < 8; q++) rw[q] = ern[e + q];
        unsigned int v[8];
#pragma unroll
        for (int q = 0; q < 8; q++) v[q] = hb[(size_t)rw[q].x * 64 + lane];
#pragma unroll
        for (int q = 0; q < 8; q++) {
            float w = __int_as_float(rw[q].y);
            if (q & 1) { c0 += w * blo(v[q]); c1 += w * bhi(v[q]); }
            else       { a0 += w * blo(v[q]); a1 += w * bhi(v[q]); }
        }
    }
    for (; e < end; e++) {
        int2 rw = ern[e];
        float w = __int_as_float(rw.y);
        unsigned int v = hb[(size_t)rw.x * 64 + lane];
        a0 += w * blo(v);
        a1 += w * bhi(v);
    }
    a0 += c0; a1 += c1;
    float2 bv = *(const float2*)&bias[2 * lane];
    a0 += bv.x;
    a1 += bv.y;
    if (relu) { a0 = fmaxf(a0, 0.f); a1 = fmaxf(a1, 0.f); }
    out[(size_t)node * 64 + lane] = (unsigned int)f2b(a0) | ((unsigned int)f2b(a1) << 16);
}

// ---------------------------------------------------------------------------
// BatchNorm stats: per-block partials, atomically folded into sums/sumsq[128].
__global__ __launch_bounds__(256) void k_bnstats(const unsigned int* __restrict__ x,
                                                 float* __restrict__ sums,
                                                 float* __restrict__ sumsq) {
    int u = threadIdx.x & 63;      // uint column (channels 2u, 2u+1)
    int strip = threadIdx.x >> 6;  // 0..3
    int r0 = blockIdx.x * 256;
    int rend = min(r0 + 256, N_NODES);
    float sl = 0.f, s2l = 0.f, sh_ = 0.f, s2h = 0.f;
    for (int r = r0 + strip; r < rend; r += 4) {
        unsigned int v = x[(size_t)r * 64 + u];
        float a = blo(v), b = bhi(v);
        sl += a; s2l += a * a;
        sh_ += b; s2h += b * b;
    }
    __shared__ float buf[4][64][4];
    buf[strip][u][0] = sl; buf[strip][u][1] = s2l;
    buf[strip][u][2] = sh_; buf[strip][u][3] = s2h;
    __syncthreads();
    if (strip == 0) {
#pragma unroll
        for (int s = 1; s < 4; s++) {
            sl += buf[s][u][0]; s2l += buf[s][u][1];
            sh_ += buf[s][u][2]; s2h += buf[s][u][3];
        }
        atomicAdd(&sums[2 * u], sl);
        atomicAdd(&sums[2 * u + 1], sh_);
        atomicAdd(&sumsq[2 * u], s2l);
        atomicAdd(&sumsq[2 * u + 1], s2h);
    }
}

// ---------------------------------------------------------------------------
// Layer-2/3 GEMM: A bf16-packed [M,64 uints], BN scale/shift computed inline
// from raw sums/sumsq in the prologue (bnfinal eliminated). K=128.
__global__ __launch_bounds__(256) void k_gemm_h(
    const unsigned int* __restrict__ Ab, const unsigned short* __restrict__ Wt,
    const float* __restrict__ sums, const float* __restrict__ sumsq,
    const float* __restrict__ g, const float* __restrict__ be,
    unsigned short* __restrict__ Out) {
    __shared__ unsigned short As[128][40];
    __shared__ unsigned short Bs[128][40];
    __shared__ float s_sc[128], s_sh[128];
    int tid = threadIdx.x;
    int m0 = blockIdx.x * 128;
    if (tid < 128) {
        const float invn = 1.0f / (float)N_NODES;
        float mu = sums[tid] * invn;
        float var = sumsq[tid] * invn - mu * mu;
        float iv = rsqrtf(var + BN_EPS);
        float sc = g[tid] * iv;
        s_sc[tid] = sc;
        s_sh[tid] = be[tid] - mu * sc;
    }
    __syncthreads();
    int srow = tid >> 1;
    int skh = (tid & 1) << 4;
    int wave = tid >> 6, lane = tid & 63;
    int wm = (wave >> 1) * 64, wn = (wave & 1) * 64;
    int l15 = lane & 15, quad = lane >> 4;
    f32x4 acc[4][4] = {};
    bool arow_ok = (m0 + srow) < N_NODES;
    const unsigned int* arow_b = Ab + (size_t)(m0 + srow) * 64 + (skh >> 1);
    const unsigned short* wrow_p = Wt + (size_t)srow * 128 + skh;
    for (int kt = 0; kt < 128; kt += 32) {
        uint4 r0 = make_uint4(0, 0, 0, 0), r1 = make_uint4(0, 0, 0, 0);
        if (arow_ok) {
            r0 = *(const uint4*)(arow_b + (kt >> 1));
            r1 = *(const uint4*)(arow_b + (kt >> 1) + 4);
        }
        unsigned int raw[8] = {r0.x, r0.y, r0.z, r0.w, r1.x, r1.y, r1.z, r1.w};
        unsigned int p[8];
#pragma unroll
        for (int q = 0; q < 8; q++) {
            int ch = kt + skh + 2 * q;
            float f0 = blo(raw[q]) * s_sc[ch] + s_sh[ch];
            float f1 = bhi(raw[q]) * s_sc[ch + 1] + s_sh[ch + 1];
            p[q] = (unsigned int)f2b(f0) | ((unsigned int)f2b(f1) << 16);
        }
        uint4 w0 = make_uint4(p[0], p[1], p[2], p[3]);
        uint4 w1 = make_uint4(p[4], p[5], p[6], p[7]);
        uint4 b0 = *(const uint4*)(wrow_p + kt);
        uint4 b1 = *(const uint4*)(wrow_p + kt + 8);
        *(uint4*)&As[srow][skh] = w0;
        *(uint4*)&As[srow][skh + 8] = w1;
        *(uint4*)&Bs[srow][skh] = b0;
        *(uint4*)&Bs[srow][skh + 8] = b1;
        __syncthreads();
        short8 a[4], b[4];
#pragma unroll
        for (int i = 0; i < 4; i++) a[i] = *(const short8*)&As[wm + i * 16 + l15][quad * 8];
#pragma unroll
        for (int j = 0; j < 4; j++) b[j] = *(const short8*)&Bs[wn + j * 16 + l15][quad * 8];
#pragma unroll
        for (int i = 0; i < 4; i++)
#pragma unroll
            for (int j = 0; j < 4; j++)
                acc[i][j] = __builtin_amdgcn_mfma_f32_16x16x32_bf16(a[i], b[j], acc[i][j], 0, 0, 0);
        __syncthreads();
    }
#pragma unroll
    for (int i = 0; i < 4; i++) {
        int mb = m0 + wm + i * 16 + quad * 4;
#pragma unroll
        for (int r = 0; r < 4; r++) {
            int m = mb + r;
            if (m < N_NODES) {
#pragma unroll
                for (int j = 0; j < 4; j++)
                    Out[(size_t)m * 128 + wn + j * 16 + l15] = f2b(acc[i][j][r]);
            }
        }
    }
}

// ---------------------------------------------------------------------------
// Head: BN3 scale/shift from raw sums (inline), x3 fp32 write, logits+softmax.
__global__ __launch_bounds__(256) void k_logits(const unsigned int* __restrict__ abuf,
                                                const float* __restrict__ sums,
                                                const float* __restrict__ sumsq,
                                                const float* __restrict__ g,
                                                const float* __restrict__ be,
                                                const float* __restrict__ linW,
                                                const float* __restrict__ linb,
                                                float* __restrict__ logits,
                                                float* __restrict__ probs,
                                                float* __restrict__ x3out) {
    __shared__ float Xs[64][130];
    __shared__ float Ws[128 * 40];
    __shared__ float s_sc[128], s_sh[128];
    int tid = threadIdx.x;
    int m0 = blockIdx.x * 64;
    if (tid < 128) {
        const float invn = 1.0f / (float)N_NODES;
        float mu = sums[tid] * invn;
        float var = sumsq[tid] * invn - mu * mu;
        float iv = rsqrtf(var + BN_EPS);
        float sc = g[tid] * iv;
        s_sc[tid] = sc;
        s_sh[tid] = be[tid] - mu * sc;
    }
    for (int q = tid; q < 1280; q += 256)
        *(float4*)&Ws[q * 4] = *(const float4*)&linW[q * 4];
    __syncthreads();
    for (int q = tid; q < 4096; q += 256) {
        int r = q >> 6, u = q & 63;
        int m = m0 + r;
        float f0 = 0.f, f1 = 0.f;
        if (m < N_NODES) {
            unsigned int v = abuf[(size_t)m * 64 + u];
            f0 = blo(v) * s_sc[2 * u] + s_sh[2 * u];
            f1 = bhi(v) * s_sc[2 * u + 1] + s_sh[2 * u + 1];
            *(float2*)&x3out[(size_t)m * 128 + 2 * u] = make_float2(f0, f1);
        }
        *(float2*)&Xs[r][2 * u] = make_float2(f0, f1);
    }
    __syncthreads();
    int r = tid >> 2;
    int cg = tid & 3;
    int cbase = cg * 10;
    float acc[10] = {};
    for (int k = 0; k < 128; k++) {
        float a = Xs[r][k];
#pragma unroll
        for (int j = 0; j < 10; j++) acc[j] += a * Ws[k * 40 + cbase + j];
    }
#pragma unroll
    for (int j = 0; j < 10; j++) acc[j] += linb[cbase + j];
    float m = acc[0];
#pragma unroll
    for (int j = 1; j < 10; j++) m = fmaxf(m, acc[j]);
    m = fmaxf(m, __shfl_xor(m, 1));
    m = fmaxf(m, __shfl_xor(m, 2));
    float ex[10];
    float s = 0.f;
#pragma unroll
    for (int j = 0; j < 10; j++) { ex[j] = expf(acc[j] - m); s += ex[j]; }
    s += __shfl_xor(s, 1);
    s += __shfl_xor(s, 2);
    float inv = 1.0f / s;
    int mrow = m0 + r;
    if (mrow < N_NODES) {
#pragma unroll
        for (int j = 0; j < 10; j++) {
            logits[(size_t)mrow * 40 + cbase + j] = acc[j];
            probs[(size_t)mrow * 40 + cbase + j] = ex[j] * inv;
        }
    }
}

// ---------------------------------------------------------------------------
extern "C" void kernel_launch(void* const* d_in, const int* in_sizes, int n_in,
                              void* d_out, int out_size, void* d_ws, size_t ws_size,
                              hipStream_t stream) {
    const float* x = (const float*)d_in[0];
    const unsigned int* eidx = (const unsigned int*)d_in[1];
    const float* ew = (const float*)d_in[2];
    const float* W1 = (const float*)d_in[3];
    const float* b1 = (const float*)d_in[4];
    const float* W2 = (const float*)d_in[5];
    const float* b2 = (const float*)d_in[6];
    const float* W3 = (const float*)d_in[7];
    const float* b3 = (const float*)d_in[8];
    const float* g1 = (const float*)d_in[9];
    const float* be1 = (const float*)d_in[10];
    const float* g2 = (const float*)d_in[11];
    const float* be2 = (const float*)d_in[12];
    const float* g3 = (const float*)d_in[13];
    const float* be3 = (const float*)d_in[14];
    const float* linW = (const float*)d_in[15];
    const float* linb = (const float*)d_in[16];

    float* out = (float*)d_out;
    float* logits = out;
    float* probs = out + (size_t)N_NODES * NCLASS;
    float* x3out = out + 2 * (size_t)N_NODES * NCLASS;

    char* ws = (char*)d_ws;
    size_t off = 0;
    auto take = [&](size_t bytes) -> char* {
        char* p = ws + off;
        off += (bytes + 255) & ~(size_t)255;
        return p;
    };
    int* row32 = (int*)take((size_t)N_EDGES * 4);
    int* col32 = (int*)take((size_t)N_EDGES * 4);
    int* slot = (int*)take((size_t)N_EDGES * 4);
    int* colptr = (int*)take((size_t)(N_NODES + 1) * 4);
    int* counts = (int*)take((size_t)N_NODES * 4);
    unsigned long long* degcnt = (unsigned long long*)take((size_t)N_NODES * 8);
    int2* ern = (int2*)take((size_t)N_EDGES * 8);
    float* dinv = (float*)take((size_t)N_NODES * 4);
    unsigned short* hbuf = (unsigned short*)take((size_t)N_NODES * NHID * 2);
    unsigned short* abuf = (unsigned short*)take((size_t)N_NODES * NHID * 2);
    unsigned short* W1t = (unsigned short*)take((size_t)512 * 128 * 2);
    unsigned short* W2t = (unsigned short*)take((size_t)128 * 128 * 2);
    unsigned short* W3t = (unsigned short*)take((size_t)128 * 128 * 2);
    float* sums = (float*)take(128 * 4);
    float* sumsq = (float*)take(128 * 4);
    int* bsum = (int*)take((size_t)SCAN_BLOCKS * 4);
    int* bpre = (int*)take((size_t)SCAN_BLOCKS * 4);
    (void)ws_size; (void)n_in; (void)in_sizes; (void)out_size;

    const int TPB = 256;
    int grid_e = EDGE_BLOCKS;
    int grid_gemm = GEMM1_BLOCKS;                 // 391
    int grid_agg = (N_NODES * 64 + TPB - 1) / TPB;
    int grid_head = (N_NODES + 63) / 64;          // 782

    // preprocessing + layer-1 GEMM overlapped with edge histogram
    k_init_node<<<SCAN_BLOCKS, TPB, 0, stream>>>(degcnt);
    k_prep_w<<<(98304 + TPB - 1) / TPB, TPB, 0, stream>>>(W1, W2, W3, W1t, W2t, W3t);
    k_fat<<<GEMM1_BLOCKS + EDGE_BLOCKS, TPB, 0, stream>>>(
        x, W1t, hbuf, eidx, ew, row32, col32, degcnt, slot);
    k_dinv<<<SCAN_BLOCKS, TPB, 0, stream>>>(degcnt, dinv, counts, bsum);
    k_scan2<<<1, TPB, 0, stream>>>(bsum, bpre, colptr);
    k_scan3<<<SCAN_BLOCKS, TPB, 0, stream>>>(counts, bpre, colptr);
    k_scatter<<<grid_e, TPB, 0, stream>>>(row32, col32, ew, dinv, colptr, slot, ern);

    // layer 1
    k_aggregate<<<grid_agg, TPB, 0, stream>>>((const unsigned int*)hbuf, colptr, ern, dinv, b1, (unsigned int*)abuf, 1, sums, sumsq);
    k_bnstats<<<BN_BLOCKS, TPB, 0, stream>>>((const unsigned int*)abuf, sums, sumsq);

    // layer 2 (BN1 computed inline in GEMM prologue from raw sums)
    k_gemm_h<<<grid_gemm, TPB, 0, stream>>>((const unsigned int*)abuf, W2t, sums, sumsq, g1, be1, hbuf);
    k_aggregate<<<grid_agg, TPB, 0, stream>>>((const unsigned int*)hbuf, colptr, ern, dinv, b2, (unsigned int*)abuf, 1, sums, sumsq);
    k_bnstats<<<BN_BLOCKS, TPB, 0, stream>>>((const unsigned int*)abuf, sums, sumsq);

    // layer 3
    k_gemm_h<<<grid_gemm, TPB, 0, stream>>>((const unsigned int*)abuf, W3t, sums, sumsq, g2, be2, hbuf);
    k_aggregate<<<grid_agg, TPB, 0, stream>>>((const unsigned int*)hbuf, colptr, ern, dinv, b3, (unsigned int*)abuf, 0, sums, sumsq);
    k_bnstats<<<BN_BLOCKS, TPB, 0, stream>>>((const unsigned int*)abuf, sums, sumsq);

    // head: BN3 apply (inline) + x3 write + logits + softmax
    k_logits<<<grid_head, TPB, 0, stream>>>((const unsigned int*)abuf, sums, sumsq, g3, be3, linW, linb, logits, probs, x3out);
}